// Round 13
// baseline (166.121 us; speedup 1.0000x reference)
//
#include <hip/hip_runtime.h>
#include <math.h>

typedef __attribute__((ext_vector_type(8))) short short8;
typedef __attribute__((ext_vector_type(4))) float float4v;

__device__ __forceinline__ unsigned short f2bf(float f) {
    unsigned int u = __builtin_bit_cast(unsigned int, f);
    u += 0x7fffu + ((u >> 16) & 1u);
    return (unsigned short)(u >> 16);
}
__device__ __forceinline__ float bf2f(unsigned short h) {
    unsigned int u = ((unsigned int)h) << 16;
    return __builtin_bit_cast(float, u);
}

#define KCH 32

// ---------- prologue: castW1 | castW2 | tr_fc | prep_cand ----------
__global__ __launch_bounds__(256) void prologue_kernel(
    const float* __restrict__ W1, const float* __restrict__ W2,
    unsigned short* __restrict__ W1h, unsigned short* __restrict__ W2h,
    const float* __restrict__ fc, unsigned short* __restrict__ fcT,
    const float* __restrict__ xyzc, float4* __restrict__ cand4,
    int M, int Cc, int nW1, int nW2, int nTR, int Mb) {
    __shared__ float t[64][65];
    int b = blockIdx.x, tid = threadIdx.x;
    if (b < nW1) {
        int q = b * 256 + tid;
        float4 v = ((const float4*)W1)[q];
        ushort4 o; o.x = f2bf(v.x); o.y = f2bf(v.y); o.z = f2bf(v.z); o.w = f2bf(v.w);
        ((ushort4*)W1h)[q] = o;
    } else if (b < nW1 + nW2) {
        int q = (b - nW1) * 256 + tid;
        float4 v = ((const float4*)W2)[q];
        ushort4 o; o.x = f2bf(v.x); o.y = f2bf(v.y); o.z = f2bf(v.z); o.w = f2bf(v.w);
        ((ushort4*)W2h)[q] = o;
    } else if (b < nW1 + nW2 + nTR) {
        int b2 = b - nW1 - nW2;
        int jb = b2 % Mb, cb = b2 / Mb;
        int j0 = jb * 64, c0 = cb * 64;
        int tx = tid & 63, ty = tid >> 6;
#pragma unroll
        for (int i = 0; i < 16; ++i)
            t[ty + 4 * i][tx] = fc[(size_t)(c0 + ty + 4 * i) * M + j0 + tx];
        __syncthreads();
#pragma unroll
        for (int i = 0; i < 16; ++i)
            fcT[(size_t)(j0 + ty + 4 * i) * Cc + c0 + tx] = f2bf(t[tx][ty + 4 * i]);
    } else {
        int j = (b - nW1 - nW2 - nTR) * 256 + tid;
        if (j < M) {
            float cx = xyzc[j], cy = xyzc[M + j], cz = xyzc[2 * M + j];
            float cc = __fadd_rn(__fadd_rn(__fmul_rn(cx, cx), __fmul_rn(cy, cy)), __fmul_rn(cz, cz));
            cand4[j] = make_float4(cx, cy, cz, cc);
        }
    }
}

// ---------- kNN pass 1: branchless top-3; thread=point, blockIdx.y=chunk ----------
__global__ __launch_bounds__(256) void knn_scan_kernel(
    const float* __restrict__ xyzf, const float4* __restrict__ cand4,
    int N, int M, float* __restrict__ candd, int* __restrict__ candi) {
    int n = blockIdx.x * 256 + threadIdx.x;
    int ch = blockIdx.y;
    float qx = xyzf[n], qy = xyzf[N + n], qz = xyzf[2 * N + n];
    float qq = __fadd_rn(__fadd_rn(__fmul_rn(qx, qx), __fmul_rn(qy, qy)), __fmul_rn(qz, qz));
    int cs = M / KCH;
    int j0 = ch * cs;
    float d0 = INFINITY, d1 = INFINITY, d2 = INFINITY;
    int i0 = 0x7fffffff, i1 = 0x7fffffff, i2 = 0x7fffffff;
#pragma unroll 8
    for (int jj = 0; jj < cs; ++jj) {
        int j = j0 + jj;                  // wave-uniform -> scalar load
        float4 c = cand4[j];
        float s  = fmaf(qz, c.z, fmaf(qy, c.y, __fmul_rn(qx, c.x)));
        float dd = __fadd_rn(__fsub_rn(qq, 2.f * s), c.w);
        // branchless sorted insert (strict <, identical semantics to nested-if version)
        bool a0 = dd < d0, a1 = dd < d1, a2 = dd < d2;
        d2 = a1 ? d1 : (a2 ? dd : d2);
        i2 = a1 ? i1 : (a2 ? j : i2);
        d1 = a0 ? d0 : (a1 ? dd : d1);
        i1 = a0 ? i0 : (a1 ? j : i1);
        d0 = a0 ? dd : d0;
        i0 = a0 ? j : i0;
    }
    size_t base = (size_t)(ch * 3) * N + n;
    candd[base] = d0; candd[base + N] = d1; candd[base + 2 * (size_t)N] = d2;
    candi[base] = i0; candi[base + N] = i1; candi[base + 2 * (size_t)N] = i2;
}

// ---------- kNN pass 2: merge chunks (lex (d,idx)), batched loads ----------
__global__ __launch_bounds__(256) void knn_merge_kernel(
    const float* __restrict__ candd, const int* __restrict__ candi,
    const float* __restrict__ xyzf, const float* __restrict__ xyzc,
    int N, int M, int* __restrict__ idx3, float* __restrict__ w3) {
    int n = blockIdx.x * 256 + threadIdx.x;
    float bd0 = INFINITY, bd1 = INFINITY, bd2 = INFINITY;
    int bi0 = 0x7fffffff, bi1 = 0x7fffffff, bi2 = 0x7fffffff;
#pragma unroll
    for (int g = 0; g < (KCH * 3) / 8; ++g) {
        float dd[8]; int ii[8];
#pragma unroll
        for (int e = 0; e < 8; ++e) {
            size_t off = (size_t)(g * 8 + e) * N + n;
            dd[e] = candd[off];
            ii[e] = candi[off];
        }
#pragma unroll
        for (int e = 0; e < 8; ++e) {
            float d = dd[e]; int i = ii[e];
            if (d < bd2 || (d == bd2 && i < bi2)) {
                if (d < bd1 || (d == bd1 && i < bi1)) {
                    bd2 = bd1; bi2 = bi1;
                    if (d < bd0 || (d == bd0 && i < bi0)) { bd1 = bd0; bi1 = bi0; bd0 = d; bi0 = i; }
                    else                                  { bd1 = d; bi1 = i; }
                } else { bd2 = d; bi2 = i; }
            }
        }
    }
    float qx = xyzf[n], qy = xyzf[N + n], qz = xyzf[2 * N + n];
    int iif[3] = {bi0, bi1, bi2};
    float u[3];
#pragma unroll
    for (int s = 0; s < 3; ++s) {
        int i = iif[s];
        float cx = xyzc[i], cy = xyzc[M + i], cz = xyzc[2 * M + i];
        float dx = __fsub_rn(qx, cx), dy = __fsub_rn(qy, cy), dz = __fsub_rn(qz, cz);
        float dd = __fadd_rn(__fadd_rn(__fmul_rn(dx, dx), __fmul_rn(dy, dy)), __fmul_rn(dz, dz));
        float dist = fmaxf(sqrtf(dd), 1e-8f);
        u[s] = 1.f / dist;
    }
    float su = __fadd_rn(__fadd_rn(u[0], u[1]), u[2]);
#pragma unroll
    for (int s = 0; s < 3; ++s) {
        idx3[n * 3 + s] = iif[s];
        w3[n * 3 + s] = u[s] / su;
    }
}

// ---------- build x: interp | tr_ff ----------
__global__ __launch_bounds__(256) void build_x_kernel(
    const unsigned short* __restrict__ fcT, const int* __restrict__ idx3,
    const float* __restrict__ w3, const float* __restrict__ ff,
    unsigned short* __restrict__ xbuf,
    int N, int Cin, int Cc, int nInterp, int cxB, int Nb) {
    __shared__ float t[64][65];
    int b = blockIdx.x, tid = threadIdx.x;
    if (b < nInterp) {
        int cx = b % cxB, n = b / cxB;
        int c = cx * 256 + tid;
        int i0 = idx3[n * 3], i1 = idx3[n * 3 + 1], i2 = idx3[n * 3 + 2];
        float w0 = w3[n * 3], w1 = w3[n * 3 + 1], w2 = w3[n * 3 + 2];
        float f0 = bf2f(fcT[(size_t)i0 * Cc + c]);
        float f1 = bf2f(fcT[(size_t)i1 * Cc + c]);
        float f2_ = bf2f(fcT[(size_t)i2 * Cc + c]);
        float v = fmaf(w2, f2_, fmaf(w1, f1, w0 * f0));
        xbuf[(size_t)n * Cin + c] = f2bf(v);
    } else {
        int b2 = b - nInterp;
        int nb = b2 % Nb, cb = b2 / Nb;
        int n0 = nb * 64, c0 = cb * 64;
        int tx = tid & 63, ty = tid >> 6;
#pragma unroll
        for (int i = 0; i < 16; ++i)
            t[ty + 4 * i][tx] = ff[(size_t)(c0 + ty + 4 * i) * N + n0 + tx];
        __syncthreads();
#pragma unroll
        for (int i = 0; i < 16; ++i)
            xbuf[(size_t)(n0 + ty + 4 * i) * Cin + Cc + c0 + tx] = f2bf(t[tx][ty + 4 * i]);
    }
}

// ---------- bf16 MFMA GEMM -> bf16 D [O][N] + per-block channel (sum,sumsq) partials ----------
#define BK 32
__global__ __launch_bounds__(256) void gemm_bf16_kernel(
    const unsigned short* __restrict__ A,  // [O][K] bf16
    const unsigned short* __restrict__ B,  // [Ntot][K] bf16
    unsigned short* __restrict__ Dh,       // [O][Ntot] bf16 (pre-BN activations)
    float* __restrict__ psumG,             // [Ntot/128][O]
    float* __restrict__ psqG,              // [Ntot/128][O]
    int K, int Ntot, int O) {
    __shared__ short As[128 * BK], Bs[128 * BK];
    int tid = threadIdx.x;
    int lane = tid & 63, wid = tid >> 6;
    int wm = wid & 1, wn = wid >> 1;
    int o0 = blockIdx.y * 128, n0 = blockIdx.x * 128;
    int r16 = lane & 15, kg = lane >> 4;
    float4v acc[4][4];
#pragma unroll
    for (int a = 0; a < 4; ++a)
#pragma unroll
        for (int b = 0; b < 4; ++b)
            acc[a][b] = (float4v){0.f, 0.f, 0.f, 0.f};
    for (int k0 = 0; k0 < K; k0 += BK) {
#pragma unroll
        for (int h = 0; h < 2; ++h) {
            int ch = tid + h * 256;
            int row = ch >> 2, kq = ch & 3;
            __builtin_amdgcn_global_load_lds(
                (const __attribute__((address_space(1))) void*)(A + (size_t)(o0 + row) * K + k0 + kq * 8),
                (__attribute__((address_space(3))) void*)&As[ch * 8], 16, 0, 0);
            __builtin_amdgcn_global_load_lds(
                (const __attribute__((address_space(1))) void*)(B + (size_t)(n0 + row) * K + k0 + kq * 8),
                (__attribute__((address_space(3))) void*)&Bs[ch * 8], 16, 0, 0);
        }
        __syncthreads();
        short8 af[4], bfr[4];
#pragma unroll
        for (int mi = 0; mi < 4; ++mi)
            af[mi] = *(const short8*)(const void*)&As[(wm * 64 + mi * 16 + r16) * BK + kg * 8];
#pragma unroll
        for (int ni = 0; ni < 4; ++ni)
            bfr[ni] = *(const short8*)(const void*)&Bs[(wn * 64 + ni * 16 + r16) * BK + kg * 8];
#pragma unroll
        for (int mi = 0; mi < 4; ++mi)
#pragma unroll
            for (int ni = 0; ni < 4; ++ni)
                acc[mi][ni] = __builtin_amdgcn_mfma_f32_16x16x32_bf16(af[mi], bfr[ni], acc[mi][ni], 0, 0, 0);
        __syncthreads();
    }
    // bf16 D write (stats below stay f32 from acc)
#pragma unroll
    for (int mi = 0; mi < 4; ++mi) {
        int obase = o0 + wm * 64 + mi * 16 + kg * 4;
#pragma unroll
        for (int ni = 0; ni < 4; ++ni) {
            int col = n0 + wn * 64 + ni * 16 + r16;
#pragma unroll
            for (int r = 0; r < 4; ++r)
                Dh[(size_t)(obase + r) * Ntot + col] = f2bf(acc[mi][ni][r]);
        }
    }
    // per-channel partials over this block's 128 cols (deterministic fixed-order)
    float2* red = (float2*)As;
#pragma unroll
    for (int mi = 0; mi < 4; ++mi) {
#pragma unroll
        for (int r = 0; r < 4; ++r) {
            float s = 0.f, q = 0.f;
#pragma unroll
            for (int ni = 0; ni < 4; ++ni) {
                float v = acc[mi][ni][r];
                s += v; q += v * v;
            }
#pragma unroll
            for (int off = 1; off <= 8; off <<= 1) {
                s += __shfl_xor(s, off);
                q += __shfl_xor(q, off);
            }
            if (r16 == 0) {
                int row = wm * 64 + mi * 16 + kg * 4 + r;
                red[row * 2 + wn] = make_float2(s, q);
            }
        }
    }
    __syncthreads();
    if (tid < 128) {
        float2 a = red[tid * 2 + 0], b = red[tid * 2 + 1];
        int o = o0 + tid;
        psumG[(size_t)blockIdx.x * O + o] = a.x + b.x;
        psqG [(size_t)blockIdx.x * O + o] = a.y + b.y;
    }
}

// ---------- layer1 apply: stats-reduce + BN + ReLU + transpose bf16 [O][N] -> [N][C] ----------
__global__ __launch_bounds__(256) void bnrelu_tr_kernel(
    const unsigned short* __restrict__ Dh, const float* __restrict__ psumG, const float* __restrict__ psqG,
    const float* __restrict__ g, const float* __restrict__ b,
    unsigned short* __restrict__ Z, int Nn, int C, int NB) {
    __shared__ float t[64][65];
    __shared__ float2 st[4][64];
    __shared__ float2 msr[64];
    int tid = threadIdx.x;
    int tx = tid & 63, ty = tid >> 6;
    int n0 = blockIdx.x * 64, o0 = blockIdx.y * 64;
    {
        int ch = tid & 63, q4 = tid >> 6;
        float s = 0.f, qq = 0.f;
        int per = NB / 4;
        for (int i = 0; i < per; ++i) {
            int bx = q4 * per + i;
            s  += psumG[(size_t)bx * C + o0 + ch];
            qq += psqG [(size_t)bx * C + o0 + ch];
        }
        st[q4][ch] = make_float2(s, qq);
    }
#pragma unroll
    for (int i = 0; i < 16; ++i)
        t[ty + 4 * i][tx] = bf2f(Dh[(size_t)(o0 + ty + 4 * i) * Nn + n0 + tx]);
    __syncthreads();
    if (tid < 64) {
        float2 a = st[0][tid], b2 = st[1][tid], c2 = st[2][tid], d2 = st[3][tid];
        float S = (a.x + b2.x) + (c2.x + d2.x);
        float Q = (a.y + b2.y) + (c2.y + d2.y);
        float m = S / Nn;
        float v = Q / Nn - m * m;
        msr[tid] = make_float2(m, rsqrtf(v + 1e-5f));
    }
    __syncthreads();
    int o = o0 + tx;
    float mm = msr[tx].x, rr = msr[tx].y, gg = g[o], bb = b[o];
#pragma unroll
    for (int i = 0; i < 16; ++i) {
        float v = t[tx][ty + 4 * i];
        v = gg * (v - mm) * rr + bb;
        v = fmaxf(v, 0.f);
        Z[(size_t)(n0 + ty + 4 * i) * C + o] = f2bf(v);
    }
}

// ---------- layer2 apply: stats-reduce + BN + ReLU; bf16 D -> f32 out ----------
__global__ __launch_bounds__(256) void bnrelu2_kernel(
    const unsigned short* __restrict__ Dh, float* __restrict__ Y,
    const float* __restrict__ psumG, const float* __restrict__ psqG,
    const float* __restrict__ g, const float* __restrict__ b, int Nn, int C, int NB) {
    __shared__ float2 red[128];
    __shared__ float2 ms;
    int c = blockIdx.y, tid = threadIdx.x;
    if (tid < NB)
        red[tid] = make_float2(psumG[(size_t)tid * C + c], psqG[(size_t)tid * C + c]);
    __syncthreads();
    for (int s2 = NB / 2; s2 > 0; s2 >>= 1) {
        if (tid < s2) {
            red[tid].x += red[tid + s2].x;
            red[tid].y += red[tid + s2].y;
        }
        __syncthreads();
    }
    if (tid == 0) {
        float m = red[0].x / Nn;
        ms = make_float2(m, rsqrtf(red[0].y / Nn - m * m + 1e-5f));
    }
    __syncthreads();
    float mm = ms.x, rr = ms.y, gg = g[c], bb = b[c];
    int q = (int)blockIdx.x * 256 + tid;           // quad index within channel
    ushort4 dv = ((const ushort4*)(Dh + (size_t)c * Nn))[q];
    float4 v;
    v.x = fmaxf(gg * (bf2f(dv.x) - mm) * rr + bb, 0.f);
    v.y = fmaxf(gg * (bf2f(dv.y) - mm) * rr + bb, 0.f);
    v.z = fmaxf(gg * (bf2f(dv.z) - mm) * rr + bb, 0.f);
    v.w = fmaxf(gg * (bf2f(dv.w) - mm) * rr + bb, 0.f);
    ((float4*)Y)[(size_t)c * (Nn >> 2) + q] = v;
}

extern "C" void kernel_launch(void* const* d_in, const int* in_sizes, int n_in,
                              void* d_out, int out_size, void* d_ws, size_t ws_size,
                              hipStream_t stream) {
    const float* xyzf = (const float*)d_in[0];
    const float* xyzc = (const float*)d_in[1];
    const float* ff   = (const float*)d_in[2];
    const float* fc   = (const float*)d_in[3];
    const float* W1   = (const float*)d_in[4];
    const float* g1   = (const float*)d_in[5];
    const float* b1   = (const float*)d_in[6];
    const float* W2   = (const float*)d_in[7];
    const float* g2   = (const float*)d_in[8];
    const float* b2   = (const float*)d_in[9];

    int N  = in_sizes[0] / 3;       // 16384
    int M  = in_sizes[1] / 3;       // 4096
    int Cf = in_sizes[2] / N;       // 256
    int Cc = in_sizes[3] / M;       // 512
    int h1 = in_sizes[5];           // 512
    int h2 = in_sizes[8];           // 512
    int Cin = Cc + Cf;              // 768
    float* out = (float*)d_out;

    // workspace carve (~48 MB)
    char* p = (char*)d_ws;
    unsigned short* W1h = (unsigned short*)p; p += (size_t)h1 * Cin * 2;
    unsigned short* W2h = (unsigned short*)p; p += (size_t)h2 * h1 * 2;
    unsigned short* fcT = (unsigned short*)p; p += (size_t)M * Cc * 2;
    int*   idx3 = (int*)p;   p += (size_t)N * 3 * sizeof(int);
    float* w3   = (float*)p; p += (size_t)N * 3 * sizeof(float);
    float4* cand4 = (float4*)p; p += (size_t)M * sizeof(float4);
    int NB = N / 128;                                   // 128 GEMM n-blocks
    float* psumG = (float*)p; p += (size_t)NB * h1 * sizeof(float);
    float* psqG  = (float*)p; p += (size_t)NB * h1 * sizeof(float);
    unsigned short* d1h = (unsigned short*)p; p += (size_t)h1 * N * 2;   // bf16 pre-BN D, both layers
    unsigned short* xbuf = (unsigned short*)p; p += (size_t)N * Cin * 2;
    // aliases inside xbuf (dead before xbuf is first written):
    float* candd = (float*)xbuf;                        // [KCH*3][N]
    int*   candi = (int*)((char*)xbuf + (size_t)KCH * 3 * N * sizeof(float));
    unsigned short* y2 = xbuf;                          // [N][h1] bf16, alias after GEMM1

    // 1. prologue
    int nW1 = h1 * Cin / 1024, nW2 = h2 * h1 / 1024;
    int Mb = M / 64, nTR = Mb * (Cc / 64), nPR = (M + 255) / 256;
    prologue_kernel<<<nW1 + nW2 + nTR + nPR, 256, 0, stream>>>(
        W1, W2, W1h, W2h, fc, fcT, xyzc, cand4, M, Cc, nW1, nW2, nTR, Mb);

    // 2-3. kNN
    knn_scan_kernel<<<dim3(N / 256, KCH), 256, 0, stream>>>(xyzf, cand4, N, M, candd, candi);
    knn_merge_kernel<<<N / 256, 256, 0, stream>>>(candd, candi, xyzf, xyzc, N, M, idx3, w3);

    // 4. build x
    int cxB = Cc / 256, nInterp = cxB * N, Nb = N / 64, nTF = Nb * (Cf / 64);
    build_x_kernel<<<nInterp + nTF, 256, 0, stream>>>(
        fcT, idx3, w3, ff, xbuf, N, Cin, Cc, nInterp, cxB, Nb);

    // 5-6. layer 1
    gemm_bf16_kernel<<<dim3(N / 128, h1 / 128), 256, 0, stream>>>(
        W1h, xbuf, d1h, psumG, psqG, Cin, N, h1);
    bnrelu_tr_kernel<<<dim3(N / 64, h1 / 64), 256, 0, stream>>>(
        d1h, psumG, psqG, g1, b1, y2, N, h1, NB);

    // 7-8. layer 2
    gemm_bf16_kernel<<<dim3(N / 128, h2 / 128), 256, 0, stream>>>(
        W2h, y2, d1h, psumG, psqG, h1, N, h2);
    bnrelu2_kernel<<<dim3(N / 1024, h2), 256, 0, stream>>>(
        d1h, out, psumG, psqG, g2, b2, N, h2, NB);
}

// Round 14
// 158.446 us; speedup vs baseline: 1.0484x; 1.0484x over previous
//
#include <hip/hip_runtime.h>
#include <math.h>

typedef __attribute__((ext_vector_type(8))) short short8;
typedef __attribute__((ext_vector_type(4))) float float4v;

__device__ __forceinline__ unsigned short f2bf(float f) {
    unsigned int u = __builtin_bit_cast(unsigned int, f);
    u += 0x7fffu + ((u >> 16) & 1u);
    return (unsigned short)(u >> 16);
}
__device__ __forceinline__ float bf2f(unsigned short h) {
    unsigned int u = ((unsigned int)h) << 16;
    return __builtin_bit_cast(float, u);
}

#define KCH 32

// ---------- prologue: castW1 | castW2 | tr_fc | prep_cand ----------
__global__ __launch_bounds__(256) void prologue_kernel(
    const float* __restrict__ W1, const float* __restrict__ W2,
    unsigned short* __restrict__ W1h, unsigned short* __restrict__ W2h,
    const float* __restrict__ fc, unsigned short* __restrict__ fcT,
    const float* __restrict__ xyzc, float4* __restrict__ cand4,
    int M, int Cc, int nW1, int nW2, int nTR, int Mb) {
    __shared__ float t[64][65];
    int b = blockIdx.x, tid = threadIdx.x;
    if (b < nW1) {
        int q = b * 256 + tid;
        float4 v = ((const float4*)W1)[q];
        ushort4 o; o.x = f2bf(v.x); o.y = f2bf(v.y); o.z = f2bf(v.z); o.w = f2bf(v.w);
        ((ushort4*)W1h)[q] = o;
    } else if (b < nW1 + nW2) {
        int q = (b - nW1) * 256 + tid;
        float4 v = ((const float4*)W2)[q];
        ushort4 o; o.x = f2bf(v.x); o.y = f2bf(v.y); o.z = f2bf(v.z); o.w = f2bf(v.w);
        ((ushort4*)W2h)[q] = o;
    } else if (b < nW1 + nW2 + nTR) {
        int b2 = b - nW1 - nW2;
        int jb = b2 % Mb, cb = b2 / Mb;
        int j0 = jb * 64, c0 = cb * 64;
        int tx = tid & 63, ty = tid >> 6;
#pragma unroll
        for (int i = 0; i < 16; ++i)
            t[ty + 4 * i][tx] = fc[(size_t)(c0 + ty + 4 * i) * M + j0 + tx];
        __syncthreads();
#pragma unroll
        for (int i = 0; i < 16; ++i)
            fcT[(size_t)(j0 + ty + 4 * i) * Cc + c0 + tx] = f2bf(t[tx][ty + 4 * i]);
    } else {
        int j = (b - nW1 - nW2 - nTR) * 256 + tid;
        if (j < M) {
            float cx = xyzc[j], cy = xyzc[M + j], cz = xyzc[2 * M + j];
            float cc = __fadd_rn(__fadd_rn(__fmul_rn(cx, cx), __fmul_rn(cy, cy)), __fmul_rn(cz, cz));
            cand4[j] = make_float4(cx, cy, cz, cc);
        }
    }
}

// ---------- kNN pass 1: LDS-staged candidates (broadcast reads), branchless top-3 ----------
__global__ __launch_bounds__(256) void knn_scan_kernel(
    const float* __restrict__ xyzf, const float4* __restrict__ cand4,
    int N, int M, float* __restrict__ candd, int* __restrict__ candi) {
    __shared__ float4 cl[128];               // chunk candidates: cs = M/KCH = 128, 2 KB
    int tid = threadIdx.x;
    int n = blockIdx.x * 256 + tid;
    int ch = blockIdx.y;
    int cs = M / KCH;
    int j0 = ch * cs;
    if (tid < cs) cl[tid] = cand4[j0 + tid];
    __syncthreads();
    float qx = xyzf[n], qy = xyzf[N + n], qz = xyzf[2 * N + n];
    float qq = __fadd_rn(__fadd_rn(__fmul_rn(qx, qx), __fmul_rn(qy, qy)), __fmul_rn(qz, qz));
    float d0 = INFINITY, d1 = INFINITY, d2 = INFINITY;
    int i0 = 0x7fffffff, i1 = 0x7fffffff, i2 = 0x7fffffff;
#pragma unroll 8
    for (int jj = 0; jj < cs; ++jj) {
        float4 c = cl[jj];                   // same addr all lanes -> LDS broadcast
        int j = j0 + jj;
        float s  = fmaf(qz, c.z, fmaf(qy, c.y, __fmul_rn(qx, c.x)));
        float dd = __fadd_rn(__fsub_rn(qq, 2.f * s), c.w);
        // branchless sorted insert (strict <, identical semantics)
        bool a0 = dd < d0, a1 = dd < d1, a2 = dd < d2;
        d2 = a1 ? d1 : (a2 ? dd : d2);
        i2 = a1 ? i1 : (a2 ? j : i2);
        d1 = a0 ? d0 : (a1 ? dd : d1);
        i1 = a0 ? i0 : (a1 ? j : i1);
        d0 = a0 ? dd : d0;
        i0 = a0 ? j : i0;
    }
    size_t base = (size_t)(ch * 3) * N + n;
    candd[base] = d0; candd[base + N] = d1; candd[base + 2 * (size_t)N] = d2;
    candi[base] = i0; candi[base + N] = i1; candi[base + 2 * (size_t)N] = i2;
}

// ---------- kNN pass 2: merge chunks (lex (d,idx)), batched loads ----------
__global__ __launch_bounds__(256) void knn_merge_kernel(
    const float* __restrict__ candd, const int* __restrict__ candi,
    const float* __restrict__ xyzf, const float* __restrict__ xyzc,
    int N, int M, int* __restrict__ idx3, float* __restrict__ w3) {
    int n = blockIdx.x * 256 + threadIdx.x;
    float bd0 = INFINITY, bd1 = INFINITY, bd2 = INFINITY;
    int bi0 = 0x7fffffff, bi1 = 0x7fffffff, bi2 = 0x7fffffff;
#pragma unroll
    for (int g = 0; g < (KCH * 3) / 8; ++g) {
        float dd[8]; int ii[8];
#pragma unroll
        for (int e = 0; e < 8; ++e) {
            size_t off = (size_t)(g * 8 + e) * N + n;
            dd[e] = candd[off];
            ii[e] = candi[off];
        }
#pragma unroll
        for (int e = 0; e < 8; ++e) {
            float d = dd[e]; int i = ii[e];
            if (d < bd2 || (d == bd2 && i < bi2)) {
                if (d < bd1 || (d == bd1 && i < bi1)) {
                    bd2 = bd1; bi2 = bi1;
                    if (d < bd0 || (d == bd0 && i < bi0)) { bd1 = bd0; bi1 = bi0; bd0 = d; bi0 = i; }
                    else                                  { bd1 = d; bi1 = i; }
                } else { bd2 = d; bi2 = i; }
            }
        }
    }
    float qx = xyzf[n], qy = xyzf[N + n], qz = xyzf[2 * N + n];
    int iif[3] = {bi0, bi1, bi2};
    float u[3];
#pragma unroll
    for (int s = 0; s < 3; ++s) {
        int i = iif[s];
        float cx = xyzc[i], cy = xyzc[M + i], cz = xyzc[2 * M + i];
        float dx = __fsub_rn(qx, cx), dy = __fsub_rn(qy, cy), dz = __fsub_rn(qz, cz);
        float dd = __fadd_rn(__fadd_rn(__fmul_rn(dx, dx), __fmul_rn(dy, dy)), __fmul_rn(dz, dz));
        float dist = fmaxf(sqrtf(dd), 1e-8f);
        u[s] = 1.f / dist;
    }
    float su = __fadd_rn(__fadd_rn(u[0], u[1]), u[2]);
#pragma unroll
    for (int s = 0; s < 3; ++s) {
        idx3[n * 3 + s] = iif[s];
        w3[n * 3 + s] = u[s] / su;
    }
}

// ---------- build x: interp | tr_ff ----------
__global__ __launch_bounds__(256) void build_x_kernel(
    const unsigned short* __restrict__ fcT, const int* __restrict__ idx3,
    const float* __restrict__ w3, const float* __restrict__ ff,
    unsigned short* __restrict__ xbuf,
    int N, int Cin, int Cc, int nInterp, int cxB, int Nb) {
    __shared__ float t[64][65];
    int b = blockIdx.x, tid = threadIdx.x;
    if (b < nInterp) {
        int cx = b % cxB, n = b / cxB;
        int c = cx * 256 + tid;
        int i0 = idx3[n * 3], i1 = idx3[n * 3 + 1], i2 = idx3[n * 3 + 2];
        float w0 = w3[n * 3], w1 = w3[n * 3 + 1], w2 = w3[n * 3 + 2];
        float f0 = bf2f(fcT[(size_t)i0 * Cc + c]);
        float f1 = bf2f(fcT[(size_t)i1 * Cc + c]);
        float f2_ = bf2f(fcT[(size_t)i2 * Cc + c]);
        float v = fmaf(w2, f2_, fmaf(w1, f1, w0 * f0));
        xbuf[(size_t)n * Cin + c] = f2bf(v);
    } else {
        int b2 = b - nInterp;
        int nb = b2 % Nb, cb = b2 / Nb;
        int n0 = nb * 64, c0 = cb * 64;
        int tx = tid & 63, ty = tid >> 6;
#pragma unroll
        for (int i = 0; i < 16; ++i)
            t[ty + 4 * i][tx] = ff[(size_t)(c0 + ty + 4 * i) * N + n0 + tx];
        __syncthreads();
#pragma unroll
        for (int i = 0; i < 16; ++i)
            xbuf[(size_t)(n0 + ty + 4 * i) * Cin + Cc + c0 + tx] = f2bf(t[tx][ty + 4 * i]);
    }
}

// ---------- bf16 MFMA GEMM -> bf16 D [O][N] + per-block channel (sum,sumsq) partials ----------
#define BK 32
__global__ __launch_bounds__(256) void gemm_bf16_kernel(
    const unsigned short* __restrict__ A,  // [O][K] bf16
    const unsigned short* __restrict__ B,  // [Ntot][K] bf16
    unsigned short* __restrict__ Dh,       // [O][Ntot] bf16 (pre-BN activations)
    float* __restrict__ psumG,             // [Ntot/128][O]
    float* __restrict__ psqG,              // [Ntot/128][O]
    int K, int Ntot, int O) {
    __shared__ short As[128 * BK], Bs[128 * BK];
    int tid = threadIdx.x;
    int lane = tid & 63, wid = tid >> 6;
    int wm = wid & 1, wn = wid >> 1;
    int o0 = blockIdx.y * 128, n0 = blockIdx.x * 128;
    int r16 = lane & 15, kg = lane >> 4;
    float4v acc[4][4];
#pragma unroll
    for (int a = 0; a < 4; ++a)
#pragma unroll
        for (int b = 0; b < 4; ++b)
            acc[a][b] = (float4v){0.f, 0.f, 0.f, 0.f};
    for (int k0 = 0; k0 < K; k0 += BK) {
#pragma unroll
        for (int h = 0; h < 2; ++h) {
            int ch = tid + h * 256;
            int row = ch >> 2, kq = ch & 3;
            __builtin_amdgcn_global_load_lds(
                (const __attribute__((address_space(1))) void*)(A + (size_t)(o0 + row) * K + k0 + kq * 8),
                (__attribute__((address_space(3))) void*)&As[ch * 8], 16, 0, 0);
            __builtin_amdgcn_global_load_lds(
                (const __attribute__((address_space(1))) void*)(B + (size_t)(n0 + row) * K + k0 + kq * 8),
                (__attribute__((address_space(3))) void*)&Bs[ch * 8], 16, 0, 0);
        }
        __syncthreads();
        short8 af[4], bfr[4];
#pragma unroll
        for (int mi = 0; mi < 4; ++mi)
            af[mi] = *(const short8*)(const void*)&As[(wm * 64 + mi * 16 + r16) * BK + kg * 8];
#pragma unroll
        for (int ni = 0; ni < 4; ++ni)
            bfr[ni] = *(const short8*)(const void*)&Bs[(wn * 64 + ni * 16 + r16) * BK + kg * 8];
#pragma unroll
        for (int mi = 0; mi < 4; ++mi)
#pragma unroll
            for (int ni = 0; ni < 4; ++ni)
                acc[mi][ni] = __builtin_amdgcn_mfma_f32_16x16x32_bf16(af[mi], bfr[ni], acc[mi][ni], 0, 0, 0);
        __syncthreads();
    }
    // bf16 D write (stats below stay f32 from acc)
#pragma unroll
    for (int mi = 0; mi < 4; ++mi) {
        int obase = o0 + wm * 64 + mi * 16 + kg * 4;
#pragma unroll
        for (int ni = 0; ni < 4; ++ni) {
            int col = n0 + wn * 64 + ni * 16 + r16;
#pragma unroll
            for (int r = 0; r < 4; ++r)
                Dh[(size_t)(obase + r) * Ntot + col] = f2bf(acc[mi][ni][r]);
        }
    }
    // per-channel partials over this block's 128 cols (deterministic fixed-order)
    float2* red = (float2*)As;
#pragma unroll
    for (int mi = 0; mi < 4; ++mi) {
#pragma unroll
        for (int r = 0; r < 4; ++r) {
            float s = 0.f, q = 0.f;
#pragma unroll
            for (int ni = 0; ni < 4; ++ni) {
                float v = acc[mi][ni][r];
                s += v; q += v * v;
            }
#pragma unroll
            for (int off = 1; off <= 8; off <<= 1) {
                s += __shfl_xor(s, off);
                q += __shfl_xor(q, off);
            }
            if (r16 == 0) {
                int row = wm * 64 + mi * 16 + kg * 4 + r;
                red[row * 2 + wn] = make_float2(s, q);
            }
        }
    }
    __syncthreads();
    if (tid < 128) {
        float2 a = red[tid * 2 + 0], b = red[tid * 2 + 1];
        int o = o0 + tid;
        psumG[(size_t)blockIdx.x * O + o] = a.x + b.x;
        psqG [(size_t)blockIdx.x * O + o] = a.y + b.y;
    }
}

// ---------- layer1 apply: stats-reduce + BN + ReLU + transpose bf16 [O][N] -> [N][C] ----------
__global__ __launch_bounds__(256) void bnrelu_tr_kernel(
    const unsigned short* __restrict__ Dh, const float* __restrict__ psumG, const float* __restrict__ psqG,
    const float* __restrict__ g, const float* __restrict__ b,
    unsigned short* __restrict__ Z, int Nn, int C, int NB) {
    __shared__ float t[64][65];
    __shared__ float2 st[4][64];
    __shared__ float2 msr[64];
    int tid = threadIdx.x;
    int tx = tid & 63, ty = tid >> 6;
    int n0 = blockIdx.x * 64, o0 = blockIdx.y * 64;
    {
        int ch = tid & 63, q4 = tid >> 6;
        float s = 0.f, qq = 0.f;
        int per = NB / 4;
        for (int i = 0; i < per; ++i) {
            int bx = q4 * per + i;
            s  += psumG[(size_t)bx * C + o0 + ch];
            qq += psqG [(size_t)bx * C + o0 + ch];
        }
        st[q4][ch] = make_float2(s, qq);
    }
#pragma unroll
    for (int i = 0; i < 16; ++i)
        t[ty + 4 * i][tx] = bf2f(Dh[(size_t)(o0 + ty + 4 * i) * Nn + n0 + tx]);
    __syncthreads();
    if (tid < 64) {
        float2 a = st[0][tid], b2 = st[1][tid], c2 = st[2][tid], d2 = st[3][tid];
        float S = (a.x + b2.x) + (c2.x + d2.x);
        float Q = (a.y + b2.y) + (c2.y + d2.y);
        float m = S / Nn;
        float v = Q / Nn - m * m;
        msr[tid] = make_float2(m, rsqrtf(v + 1e-5f));
    }
    __syncthreads();
    int o = o0 + tx;
    float mm = msr[tx].x, rr = msr[tx].y, gg = g[o], bb = b[o];
#pragma unroll
    for (int i = 0; i < 16; ++i) {
        float v = t[tx][ty + 4 * i];
        v = gg * (v - mm) * rr + bb;
        v = fmaxf(v, 0.f);
        Z[(size_t)(n0 + ty + 4 * i) * C + o] = f2bf(v);
    }
}

// ---------- layer2 apply: stats-reduce + BN + ReLU; bf16 D -> f32 out ----------
__global__ __launch_bounds__(256) void bnrelu2_kernel(
    const unsigned short* __restrict__ Dh, float* __restrict__ Y,
    const float* __restrict__ psumG, const float* __restrict__ psqG,
    const float* __restrict__ g, const float* __restrict__ b, int Nn, int C, int NB) {
    __shared__ float2 red[128];
    __shared__ float2 ms;
    int c = blockIdx.y, tid = threadIdx.x;
    if (tid < NB)
        red[tid] = make_float2(psumG[(size_t)tid * C + c], psqG[(size_t)tid * C + c]);
    __syncthreads();
    for (int s2 = NB / 2; s2 > 0; s2 >>= 1) {
        if (tid < s2) {
            red[tid].x += red[tid + s2].x;
            red[tid].y += red[tid + s2].y;
        }
        __syncthreads();
    }
    if (tid == 0) {
        float m = red[0].x / Nn;
        ms = make_float2(m, rsqrtf(red[0].y / Nn - m * m + 1e-5f));
    }
    __syncthreads();
    float mm = ms.x, rr = ms.y, gg = g[c], bb = b[c];
    int q = (int)blockIdx.x * 256 + tid;           // quad index within channel
    ushort4 dv = ((const ushort4*)(Dh + (size_t)c * Nn))[q];
    float4 v;
    v.x = fmaxf(gg * (bf2f(dv.x) - mm) * rr + bb, 0.f);
    v.y = fmaxf(gg * (bf2f(dv.y) - mm) * rr + bb, 0.f);
    v.z = fmaxf(gg * (bf2f(dv.z) - mm) * rr + bb, 0.f);
    v.w = fmaxf(gg * (bf2f(dv.w) - mm) * rr + bb, 0.f);
    ((float4*)Y)[(size_t)c * (Nn >> 2) + q] = v;
}

extern "C" void kernel_launch(void* const* d_in, const int* in_sizes, int n_in,
                              void* d_out, int out_size, void* d_ws, size_t ws_size,
                              hipStream_t stream) {
    const float* xyzf = (const float*)d_in[0];
    const float* xyzc = (const float*)d_in[1];
    const float* ff   = (const float*)d_in[2];
    const float* fc   = (const float*)d_in[3];
    const float* W1   = (const float*)d_in[4];
    const float* g1   = (const float*)d_in[5];
    const float* b1   = (const float*)d_in[6];
    const float* W2   = (const float*)d_in[7];
    const float* g2   = (const float*)d_in[8];
    const float* b2   = (const float*)d_in[9];

    int N  = in_sizes[0] / 3;       // 16384
    int M  = in_sizes[1] / 3;       // 4096
    int Cf = in_sizes[2] / N;       // 256
    int Cc = in_sizes[3] / M;       // 512
    int h1 = in_sizes[5];           // 512
    int h2 = in_sizes[8];           // 512
    int Cin = Cc + Cf;              // 768
    float* out = (float*)d_out;

    // workspace carve (~48 MB)
    char* p = (char*)d_ws;
    unsigned short* W1h = (unsigned short*)p; p += (size_t)h1 * Cin * 2;
    unsigned short* W2h = (unsigned short*)p; p += (size_t)h2 * h1 * 2;
    unsigned short* fcT = (unsigned short*)p; p += (size_t)M * Cc * 2;
    int*   idx3 = (int*)p;   p += (size_t)N * 3 * sizeof(int);
    float* w3   = (float*)p; p += (size_t)N * 3 * sizeof(float);
    float4* cand4 = (float4*)p; p += (size_t)M * sizeof(float4);
    int NB = N / 128;                                   // 128 GEMM n-blocks
    float* psumG = (float*)p; p += (size_t)NB * h1 * sizeof(float);
    float* psqG  = (float*)p; p += (size_t)NB * h1 * sizeof(float);
    unsigned short* d1h = (unsigned short*)p; p += (size_t)h1 * N * 2;   // bf16 pre-BN D, both layers
    unsigned short* xbuf = (unsigned short*)p; p += (size_t)N * Cin * 2;
    // aliases inside xbuf (dead before xbuf is first written):
    float* candd = (float*)xbuf;                        // [KCH*3][N]
    int*   candi = (int*)((char*)xbuf + (size_t)KCH * 3 * N * sizeof(float));
    unsigned short* y2 = xbuf;                          // [N][h1] bf16, alias after GEMM1

    // 1. prologue
    int nW1 = h1 * Cin / 1024, nW2 = h2 * h1 / 1024;
    int Mb = M / 64, nTR = Mb * (Cc / 64), nPR = (M + 255) / 256;
    prologue_kernel<<<nW1 + nW2 + nTR + nPR, 256, 0, stream>>>(
        W1, W2, W1h, W2h, fc, fcT, xyzc, cand4, M, Cc, nW1, nW2, nTR, Mb);

    // 2-3. kNN
    knn_scan_kernel<<<dim3(N / 256, KCH), 256, 0, stream>>>(xyzf, cand4, N, M, candd, candi);
    knn_merge_kernel<<<N / 256, 256, 0, stream>>>(candd, candi, xyzf, xyzc, N, M, idx3, w3);

    // 4. build x
    int cxB = Cc / 256, nInterp = cxB * N, Nb = N / 64, nTF = Nb * (Cf / 64);
    build_x_kernel<<<nInterp + nTF, 256, 0, stream>>>(
        fcT, idx3, w3, ff, xbuf, N, Cin, Cc, nInterp, cxB, Nb);

    // 5-6. layer 1
    gemm_bf16_kernel<<<dim3(N / 128, h1 / 128), 256, 0, stream>>>(
        W1h, xbuf, d1h, psumG, psqG, Cin, N, h1);
    bnrelu_tr_kernel<<<dim3(N / 64, h1 / 64), 256, 0, stream>>>(
        d1h, psumG, psqG, g1, b1, y2, N, h1, NB);

    // 7-8. layer 2
    gemm_bf16_kernel<<<dim3(N / 128, h2 / 128), 256, 0, stream>>>(
        W2h, y2, d1h, psumG, psqG, h1, N, h2);
    bnrelu2_kernel<<<dim3(N / 1024, h2), 256, 0, stream>>>(
        d1h, out, psumG, psqG, g2, b2, N, h2, NB);
}

// Round 16
// 154.195 us; speedup vs baseline: 1.0773x; 1.0276x over previous
//
#include <hip/hip_runtime.h>
#include <math.h>

typedef __attribute__((ext_vector_type(8))) short short8;
typedef __attribute__((ext_vector_type(4))) float float4v;

__device__ __forceinline__ unsigned short f2bf(float f) {
    unsigned int u = __builtin_bit_cast(unsigned int, f);
    u += 0x7fffu + ((u >> 16) & 1u);
    return (unsigned short)(u >> 16);
}
__device__ __forceinline__ float bf2f(unsigned short h) {
    unsigned int u = ((unsigned int)h) << 16;
    return __builtin_bit_cast(float, u);
}

#define KCH 32

// ---------- kernel 1: prologue (castW1|castW2|tr_fc) blocks, then scan blocks ----------
__global__ __launch_bounds__(256) void scan_pro_kernel(
    const float* __restrict__ W1, const float* __restrict__ W2,
    unsigned short* __restrict__ W1h, unsigned short* __restrict__ W2h,
    const float* __restrict__ fc, unsigned short* __restrict__ fcT,
    const float* __restrict__ xyzf, const float* __restrict__ xyzc,
    float* __restrict__ candd, int* __restrict__ candi,
    int N, int M, int Cc, int nW1, int nW2, int nTR, int Mb) {
    __shared__ float4 smem4[1040];           // 16640 B: tr_fc tile or scan candidates
    int b = blockIdx.x, tid = threadIdx.x;
    int nPro = nW1 + nW2 + nTR;
    if (b < nW1) {
        int q = b * 256 + tid;
        float4 v = ((const float4*)W1)[q];
        ushort4 o; o.x = f2bf(v.x); o.y = f2bf(v.y); o.z = f2bf(v.z); o.w = f2bf(v.w);
        ((ushort4*)W1h)[q] = o;
    } else if (b < nW1 + nW2) {
        int q = (b - nW1) * 256 + tid;
        float4 v = ((const float4*)W2)[q];
        ushort4 o; o.x = f2bf(v.x); o.y = f2bf(v.y); o.z = f2bf(v.z); o.w = f2bf(v.w);
        ((ushort4*)W2h)[q] = o;
    } else if (b < nPro) {
        float (*t)[65] = (float(*)[65])smem4;
        int b2 = b - nW1 - nW2;
        int jb = b2 % Mb, cb = b2 / Mb;
        int j0 = jb * 64, c0 = cb * 64;
        int tx = tid & 63, ty = tid >> 6;
#pragma unroll
        for (int i = 0; i < 16; ++i)
            t[ty + 4 * i][tx] = fc[(size_t)(c0 + ty + 4 * i) * M + j0 + tx];
        __syncthreads();
#pragma unroll
        for (int i = 0; i < 16; ++i)
            fcT[(size_t)(j0 + ty + 4 * i) * Cc + c0 + tx] = f2bf(t[tx][ty + 4 * i]);
    } else {
        // ---- kNN scan: LDS-staged candidates (broadcast reads), branchless top-3 ----
        float4* cl = smem4;                  // first 2 KB
        int b2 = b - nPro;
        int n = (b2 & 63) * 256 + tid;       // 64 n-blocks
        int ch = b2 >> 6;                    // KCH chunks
        int cs = M / KCH;                    // 128
        int j0 = ch * cs;
        if (tid < cs) {
            int j = j0 + tid;
            float cx = xyzc[j], cy = xyzc[M + j], cz = xyzc[2 * M + j];
            float cc = __fadd_rn(__fadd_rn(__fmul_rn(cx, cx), __fmul_rn(cy, cy)), __fmul_rn(cz, cz));
            cl[tid] = make_float4(cx, cy, cz, cc);
        }
        __syncthreads();
        float qx = xyzf[n], qy = xyzf[N + n], qz = xyzf[2 * N + n];
        float qq = __fadd_rn(__fadd_rn(__fmul_rn(qx, qx), __fmul_rn(qy, qy)), __fmul_rn(qz, qz));
        float d0 = INFINITY, d1 = INFINITY, d2 = INFINITY;
        int i0 = 0x7fffffff, i1 = 0x7fffffff, i2 = 0x7fffffff;
#pragma unroll 8
        for (int jj = 0; jj < cs; ++jj) {
            float4 c = cl[jj];               // same addr all lanes -> LDS broadcast
            int j = j0 + jj;
            float s  = fmaf(qz, c.z, fmaf(qy, c.y, __fmul_rn(qx, c.x)));
            float dd = __fadd_rn(__fsub_rn(qq, 2.f * s), c.w);
            bool a0 = dd < d0, a1 = dd < d1, a2 = dd < d2;
            d2 = a1 ? d1 : (a2 ? dd : d2);
            i2 = a1 ? i1 : (a2 ? j : i2);
            d1 = a0 ? d0 : (a1 ? dd : d1);
            i1 = a0 ? i0 : (a1 ? j : i1);
            d0 = a0 ? dd : d0;
            i0 = a0 ? j : i0;
        }
        size_t base = (size_t)(ch * 3) * N + n;
        candd[base] = d0; candd[base + N] = d1; candd[base + 2 * (size_t)N] = d2;
        candi[base] = i0; candi[base + N] = i1; candi[base + 2 * (size_t)N] = i2;
    }
}

// ---------- kernel 2: merge blocks first, then tr_ff blocks (independent) ----------
// NOTE: candd/candi alias d1h (NOT xbuf) so tr_ff's xbuf writes cannot race merge's reads.
__global__ __launch_bounds__(256) void merge_trff_kernel(
    const float* __restrict__ candd, const int* __restrict__ candi,
    const float* __restrict__ xyzf, const float* __restrict__ xyzc,
    const float* __restrict__ ff, unsigned short* __restrict__ xbuf,
    int* __restrict__ idx3, float* __restrict__ w3,
    int N, int M, int Cin, int Cc, int nMerge, int Nb) {
    __shared__ float t[64][65];
    int b = blockIdx.x, tid = threadIdx.x;
    if (b < nMerge) {
        int n = b * 256 + tid;
        float bd0 = INFINITY, bd1 = INFINITY, bd2 = INFINITY;
        int bi0 = 0x7fffffff, bi1 = 0x7fffffff, bi2 = 0x7fffffff;
#pragma unroll
        for (int g = 0; g < (KCH * 3) / 8; ++g) {
            float dd[8]; int ii[8];
#pragma unroll
            for (int e = 0; e < 8; ++e) {
                size_t off = (size_t)(g * 8 + e) * N + n;
                dd[e] = candd[off];
                ii[e] = candi[off];
            }
#pragma unroll
            for (int e = 0; e < 8; ++e) {
                float d = dd[e]; int i = ii[e];
                if (d < bd2 || (d == bd2 && i < bi2)) {
                    if (d < bd1 || (d == bd1 && i < bi1)) {
                        bd2 = bd1; bi2 = bi1;
                        if (d < bd0 || (d == bd0 && i < bi0)) { bd1 = bd0; bi1 = bi0; bd0 = d; bi0 = i; }
                        else                                  { bd1 = d; bi1 = i; }
                    } else { bd2 = d; bi2 = i; }
                }
            }
        }
        float qx = xyzf[n], qy = xyzf[N + n], qz = xyzf[2 * N + n];
        int iif[3] = {bi0, bi1, bi2};
        float u[3];
#pragma unroll
        for (int s = 0; s < 3; ++s) {
            int i = iif[s];
            float cx = xyzc[i], cy = xyzc[M + i], cz = xyzc[2 * M + i];
            float dx = __fsub_rn(qx, cx), dy = __fsub_rn(qy, cy), dz = __fsub_rn(qz, cz);
            float dd = __fadd_rn(__fadd_rn(__fmul_rn(dx, dx), __fmul_rn(dy, dy)), __fmul_rn(dz, dz));
            float dist = fmaxf(sqrtf(dd), 1e-8f);
            u[s] = 1.f / dist;
        }
        float su = __fadd_rn(__fadd_rn(u[0], u[1]), u[2]);
#pragma unroll
        for (int s = 0; s < 3; ++s) {
            idx3[n * 3 + s] = iif[s];
            w3[n * 3 + s] = u[s] / su;
        }
    } else {
        int b2 = b - nMerge;
        int nb = b2 % Nb, cb = b2 / Nb;
        int n0 = nb * 64, c0 = cb * 64;
        int tx = tid & 63, ty = tid >> 6;
#pragma unroll
        for (int i = 0; i < 16; ++i)
            t[ty + 4 * i][tx] = ff[(size_t)(c0 + ty + 4 * i) * N + n0 + tx];
        __syncthreads();
#pragma unroll
        for (int i = 0; i < 16; ++i)
            xbuf[(size_t)(n0 + ty + 4 * i) * Cin + Cc + c0 + tx] = f2bf(t[tx][ty + 4 * i]);
    }
}

// ---------- interp: xbuf[n][c] = sum_s w_s * fcT[i_s][c], c in [0,Cc) ----------
__global__ __launch_bounds__(256) void interp_kernel(
    const unsigned short* __restrict__ fcT, const int* __restrict__ idx3,
    const float* __restrict__ w3, unsigned short* __restrict__ xbuf,
    int Cin, int Cc, int cxB) {
    int b = blockIdx.x, tid = threadIdx.x;
    int cx = b % cxB, n = b / cxB;
    int c = cx * 256 + tid;
    int i0 = idx3[n * 3], i1 = idx3[n * 3 + 1], i2 = idx3[n * 3 + 2];
    float w0 = w3[n * 3], w1 = w3[n * 3 + 1], w2 = w3[n * 3 + 2];
    float f0 = bf2f(fcT[(size_t)i0 * Cc + c]);
    float f1 = bf2f(fcT[(size_t)i1 * Cc + c]);
    float f2_ = bf2f(fcT[(size_t)i2 * Cc + c]);
    float v = fmaf(w2, f2_, fmaf(w1, f1, w0 * f0));
    xbuf[(size_t)n * Cin + c] = f2bf(v);
}

// ---------- bf16 MFMA GEMM -> bf16 D [O][N] + per-block channel (sum,sumsq) partials ----------
#define BK 32
__global__ __launch_bounds__(256) void gemm_bf16_kernel(
    const unsigned short* __restrict__ A,  // [O][K] bf16
    const unsigned short* __restrict__ B,  // [Ntot][K] bf16
    unsigned short* __restrict__ Dh,       // [O][Ntot] bf16 (pre-BN activations)
    float* __restrict__ psumG,             // [Ntot/128][O]
    float* __restrict__ psqG,              // [Ntot/128][O]
    int K, int Ntot, int O) {
    __shared__ short As[128 * BK], Bs[128 * BK];
    int tid = threadIdx.x;
    int lane = tid & 63, wid = tid >> 6;
    int wm = wid & 1, wn = wid >> 1;
    int o0 = blockIdx.y * 128, n0 = blockIdx.x * 128;
    int r16 = lane & 15, kg = lane >> 4;
    float4v acc[4][4];
#pragma unroll
    for (int a = 0; a < 4; ++a)
#pragma unroll
        for (int b = 0; b < 4; ++b)
            acc[a][b] = (float4v){0.f, 0.f, 0.f, 0.f};
    for (int k0 = 0; k0 < K; k0 += BK) {
#pragma unroll
        for (int h = 0; h < 2; ++h) {
            int ch = tid + h * 256;
            int row = ch >> 2, kq = ch & 3;
            __builtin_amdgcn_global_load_lds(
                (const __attribute__((address_space(1))) void*)(A + (size_t)(o0 + row) * K + k0 + kq * 8),
                (__attribute__((address_space(3))) void*)&As[ch * 8], 16, 0, 0);
            __builtin_amdgcn_global_load_lds(
                (const __attribute__((address_space(1))) void*)(B + (size_t)(n0 + row) * K + k0 + kq * 8),
                (__attribute__((address_space(3))) void*)&Bs[ch * 8], 16, 0, 0);
        }
        __syncthreads();
        short8 af[4], bfr[4];
#pragma unroll
        for (int mi = 0; mi < 4; ++mi)
            af[mi] = *(const short8*)(const void*)&As[(wm * 64 + mi * 16 + r16) * BK + kg * 8];
#pragma unroll
        for (int ni = 0; ni < 4; ++ni)
            bfr[ni] = *(const short8*)(const void*)&Bs[(wn * 64 + ni * 16 + r16) * BK + kg * 8];
#pragma unroll
        for (int mi = 0; mi < 4; ++mi)
#pragma unroll
            for (int ni = 0; ni < 4; ++ni)
                acc[mi][ni] = __builtin_amdgcn_mfma_f32_16x16x32_bf16(af[mi], bfr[ni], acc[mi][ni], 0, 0, 0);
        __syncthreads();
    }
#pragma unroll
    for (int mi = 0; mi < 4; ++mi) {
        int obase = o0 + wm * 64 + mi * 16 + kg * 4;
#pragma unroll
        for (int ni = 0; ni < 4; ++ni) {
            int col = n0 + wn * 64 + ni * 16 + r16;
#pragma unroll
            for (int r = 0; r < 4; ++r)
                Dh[(size_t)(obase + r) * Ntot + col] = f2bf(acc[mi][ni][r]);
        }
    }
    float2* red = (float2*)As;
#pragma unroll
    for (int mi = 0; mi < 4; ++mi) {
#pragma unroll
        for (int r = 0; r < 4; ++r) {
            float s = 0.f, q = 0.f;
#pragma unroll
            for (int ni = 0; ni < 4; ++ni) {
                float v = acc[mi][ni][r];
                s += v; q += v * v;
            }
#pragma unroll
            for (int off = 1; off <= 8; off <<= 1) {
                s += __shfl_xor(s, off);
                q += __shfl_xor(q, off);
            }
            if (r16 == 0) {
                int row = wm * 64 + mi * 16 + kg * 4 + r;
                red[row * 2 + wn] = make_float2(s, q);
            }
        }
    }
    __syncthreads();
    if (tid < 128) {
        float2 a = red[tid * 2 + 0], b = red[tid * 2 + 1];
        int o = o0 + tid;
        psumG[(size_t)blockIdx.x * O + o] = a.x + b.x;
        psqG [(size_t)blockIdx.x * O + o] = a.y + b.y;
    }
}

// ---------- layer1 apply: stats-reduce + BN + ReLU + transpose bf16 [O][N] -> [N][C] ----------
__global__ __launch_bounds__(256) void bnrelu_tr_kernel(
    const unsigned short* __restrict__ Dh, const float* __restrict__ psumG, const float* __restrict__ psqG,
    const float* __restrict__ g, const float* __restrict__ b,
    unsigned short* __restrict__ Z, int Nn, int C, int NB) {
    __shared__ float t[64][65];
    __shared__ float2 st[4][64];
    __shared__ float2 msr[64];
    int tid = threadIdx.x;
    int tx = tid & 63, ty = tid >> 6;
    int n0 = blockIdx.x * 64, o0 = blockIdx.y * 64;
    {
        int ch = tid & 63, q4 = tid >> 6;
        float s = 0.f, qq = 0.f;
        int per = NB / 4;
        for (int i = 0; i < per; ++i) {
            int bx = q4 * per + i;
            s  += psumG[(size_t)bx * C + o0 + ch];
            qq += psqG [(size_t)bx * C + o0 + ch];
        }
        st[q4][ch] = make_float2(s, qq);
    }
#pragma unroll
    for (int i = 0; i < 16; ++i)
        t[ty + 4 * i][tx] = bf2f(Dh[(size_t)(o0 + ty + 4 * i) * Nn + n0 + tx]);
    __syncthreads();
    if (tid < 64) {
        float2 a = st[0][tid], b2 = st[1][tid], c2 = st[2][tid], d2 = st[3][tid];
        float S = (a.x + b2.x) + (c2.x + d2.x);
        float Q = (a.y + b2.y) + (c2.y + d2.y);
        float m = S / Nn;
        float v = Q / Nn - m * m;
        msr[tid] = make_float2(m, rsqrtf(v + 1e-5f));
    }
    __syncthreads();
    int o = o0 + tx;
    float mm = msr[tx].x, rr = msr[tx].y, gg = g[o], bb = b[o];
#pragma unroll
    for (int i = 0; i < 16; ++i) {
        float v = t[tx][ty + 4 * i];
        v = gg * (v - mm) * rr + bb;
        v = fmaxf(v, 0.f);
        Z[(size_t)(n0 + ty + 4 * i) * C + o] = f2bf(v);
    }
}

// ---------- layer2 apply: stats-reduce + BN + ReLU; bf16 D -> f32 out ----------
__global__ __launch_bounds__(256) void bnrelu2_kernel(
    const unsigned short* __restrict__ Dh, float* __restrict__ Y,
    const float* __restrict__ psumG, const float* __restrict__ psqG,
    const float* __restrict__ g, const float* __restrict__ b, int Nn, int C, int NB) {
    __shared__ float2 red[128];
    __shared__ float2 ms;
    int c = blockIdx.y, tid = threadIdx.x;
    if (tid < NB)
        red[tid] = make_float2(psumG[(size_t)tid * C + c], psqG[(size_t)tid * C + c]);
    __syncthreads();
    for (int s2 = NB / 2; s2 > 0; s2 >>= 1) {
        if (tid < s2) {
            red[tid].x += red[tid + s2].x;
            red[tid].y += red[tid + s2].y;
        }
        __syncthreads();
    }
    if (tid == 0) {
        float m = red[0].x / Nn;
        ms = make_float2(m, rsqrtf(red[0].y / Nn - m * m + 1e-5f));
    }
    __syncthreads();
    float mm = ms.x, rr = ms.y, gg = g[c], bb = b[c];
    int q = (int)blockIdx.x * 256 + tid;
    ushort4 dv = ((const ushort4*)(Dh + (size_t)c * Nn))[q];
    float4 v;
    v.x = fmaxf(gg * (bf2f(dv.x) - mm) * rr + bb, 0.f);
    v.y = fmaxf(gg * (bf2f(dv.y) - mm) * rr + bb, 0.f);
    v.z = fmaxf(gg * (bf2f(dv.z) - mm) * rr + bb, 0.f);
    v.w = fmaxf(gg * (bf2f(dv.w) - mm) * rr + bb, 0.f);
    ((float4*)Y)[(size_t)c * (Nn >> 2) + q] = v;
}

extern "C" void kernel_launch(void* const* d_in, const int* in_sizes, int n_in,
                              void* d_out, int out_size, void* d_ws, size_t ws_size,
                              hipStream_t stream) {
    const float* xyzf = (const float*)d_in[0];
    const float* xyzc = (const float*)d_in[1];
    const float* ff   = (const float*)d_in[2];
    const float* fc   = (const float*)d_in[3];
    const float* W1   = (const float*)d_in[4];
    const float* g1   = (const float*)d_in[5];
    const float* b1   = (const float*)d_in[6];
    const float* W2   = (const float*)d_in[7];
    const float* g2   = (const float*)d_in[8];
    const float* b2   = (const float*)d_in[9];

    int N  = in_sizes[0] / 3;       // 16384
    int M  = in_sizes[1] / 3;       // 4096
    int Cf = in_sizes[2] / N;       // 256
    int Cc = in_sizes[3] / M;       // 512
    int h1 = in_sizes[5];           // 512
    int h2 = in_sizes[8];           // 512
    int Cin = Cc + Cf;              // 768
    float* out = (float*)d_out;

    // workspace carve (~48 MB)
    char* p = (char*)d_ws;
    unsigned short* W1h = (unsigned short*)p; p += (size_t)h1 * Cin * 2;
    unsigned short* W2h = (unsigned short*)p; p += (size_t)h2 * h1 * 2;
    unsigned short* fcT = (unsigned short*)p; p += (size_t)M * Cc * 2;
    int*   idx3 = (int*)p;   p += (size_t)N * 3 * sizeof(int);
    float* w3   = (float*)p; p += (size_t)N * 3 * sizeof(float);
    int NB = N / 128;                                   // 128 GEMM n-blocks
    float* psumG = (float*)p; p += (size_t)NB * h1 * sizeof(float);
    float* psqG  = (float*)p; p += (size_t)NB * h1 * sizeof(float);
    unsigned short* d1h = (unsigned short*)p; p += (size_t)h1 * N * 2;   // bf16 pre-BN D
    unsigned short* xbuf = (unsigned short*)p; p += (size_t)N * Cin * 2;
    // cand aliases live in d1h (dead until gemm1) — NOT xbuf, since kernel 2's
    // tr_ff blocks write xbuf concurrently with merge blocks reading cand.
    float* candd = (float*)d1h;                         // [KCH*3][N] = 6.29 MB
    int*   candi = (int*)((char*)d1h + (size_t)KCH * 3 * N * sizeof(float));  // + 6.29 MB <= 16.78 MB
    unsigned short* y2 = xbuf;                          // [N][h1] bf16, alias after GEMM1

    // 1. prologue + kNN scan (independent work fused; prologue blocks first)
    int nW1 = h1 * Cin / 1024, nW2 = h2 * h1 / 1024;
    int Mb = M / 64, nTR = Mb * (Cc / 64);
    int nPro = nW1 + nW2 + nTR;
    scan_pro_kernel<<<nPro + (N / 256) * KCH, 256, 0, stream>>>(
        W1, W2, W1h, W2h, fc, fcT, xyzf, xyzc, candd, candi,
        N, M, Cc, nW1, nW2, nTR, Mb);

    // 2. merge + tr_ff (independent; merge blocks first)
    int nMerge = N / 256, Nb = N / 64, nTF = Nb * (Cf / 64);
    merge_trff_kernel<<<nMerge + nTF, 256, 0, stream>>>(
        candd, candi, xyzf, xyzc, ff, xbuf, idx3, w3, N, M, Cin, Cc, nMerge, Nb);

    // 3. interp
    int cxB = Cc / 256;
    interp_kernel<<<cxB * N, 256, 0, stream>>>(fcT, idx3, w3, xbuf, Cin, Cc, cxB);

    // 4-5. layer 1
    gemm_bf16_kernel<<<dim3(N / 128, h1 / 128), 256, 0, stream>>>(
        W1h, xbuf, d1h, psumG, psqG, Cin, N, h1);
    bnrelu_tr_kernel<<<dim3(N / 64, h1 / 64), 256, 0, stream>>>(
        d1h, psumG, psqG, g1, b1, y2, N, h1, NB);

    // 6-7. layer 2
    gemm_bf16_kernel<<<dim3(N / 128, h2 / 128), 256, 0, stream>>>(
        W2h, y2, d1h, psumG, psqG, h1, N, h2);
    bnrelu2_kernel<<<dim3(N / 1024, h2), 256, 0, stream>>>(
        d1h, out, psumG, psqG, g2, b2, N, h2, NB);
}

// Round 17
// 147.387 us; speedup vs baseline: 1.1271x; 1.0462x over previous
//
#include <hip/hip_runtime.h>
#include <math.h>

typedef __attribute__((ext_vector_type(8))) short short8;
typedef __attribute__((ext_vector_type(4))) float float4v;

__device__ __forceinline__ unsigned short f2bf(float f) {
    unsigned int u = __builtin_bit_cast(unsigned int, f);
    u += 0x7fffu + ((u >> 16) & 1u);
    return (unsigned short)(u >> 16);
}
__device__ __forceinline__ float bf2f(unsigned short h) {
    unsigned int u = ((unsigned int)h) << 16;
    return __builtin_bit_cast(float, u);
}

#define KCH 32

// ---------- kernel 1: prologue (castW1|castW2|tr_fc) blocks, then scan blocks ----------
__global__ __launch_bounds__(256) void scan_pro_kernel(
    const float* __restrict__ W1, const float* __restrict__ W2,
    unsigned short* __restrict__ W1h, unsigned short* __restrict__ W2h,
    const float* __restrict__ fc, unsigned short* __restrict__ fcT,
    const float* __restrict__ xyzf, const float* __restrict__ xyzc,
    float* __restrict__ candd, int* __restrict__ candi,
    int N, int M, int Cc, int nW1, int nW2, int nTR, int Mb) {
    __shared__ float4 smem4[1040];           // 16640 B: tr_fc tile or scan candidates
    int b = blockIdx.x, tid = threadIdx.x;
    int nPro = nW1 + nW2 + nTR;
    if (b < nW1) {
        int q = b * 256 + tid;
        float4 v = ((const float4*)W1)[q];
        ushort4 o; o.x = f2bf(v.x); o.y = f2bf(v.y); o.z = f2bf(v.z); o.w = f2bf(v.w);
        ((ushort4*)W1h)[q] = o;
    } else if (b < nW1 + nW2) {
        int q = (b - nW1) * 256 + tid;
        float4 v = ((const float4*)W2)[q];
        ushort4 o; o.x = f2bf(v.x); o.y = f2bf(v.y); o.z = f2bf(v.z); o.w = f2bf(v.w);
        ((ushort4*)W2h)[q] = o;
    } else if (b < nPro) {
        float (*t)[65] = (float(*)[65])smem4;
        int b2 = b - nW1 - nW2;
        int jb = b2 % Mb, cb = b2 / Mb;
        int j0 = jb * 64, c0 = cb * 64;
        int tx = tid & 63, ty = tid >> 6;
#pragma unroll
        for (int i = 0; i < 16; ++i)
            t[ty + 4 * i][tx] = fc[(size_t)(c0 + ty + 4 * i) * M + j0 + tx];
        __syncthreads();
#pragma unroll
        for (int i = 0; i < 16; ++i)
            fcT[(size_t)(j0 + ty + 4 * i) * Cc + c0 + tx] = f2bf(t[tx][ty + 4 * i]);
    } else {
        // ---- kNN scan: LDS-staged candidates (broadcast reads), min/med3 top-3 ----
        float4* cl = smem4;                  // first 2 KB
        int b2 = b - nPro;
        int n = (b2 & 63) * 256 + tid;       // 64 n-blocks
        int ch = b2 >> 6;                    // KCH chunks
        int cs = M / KCH;                    // 128
        int j0 = ch * cs;
        if (tid < cs) {
            int j = j0 + tid;
            float cx = xyzc[j], cy = xyzc[M + j], cz = xyzc[2 * M + j];
            float cc = __fadd_rn(__fadd_rn(__fmul_rn(cx, cx), __fmul_rn(cy, cy)), __fmul_rn(cz, cz));
            cl[tid] = make_float4(cx, cy, cz, cc);
        }
        __syncthreads();
        float qx = xyzf[n], qy = xyzf[N + n], qz = xyzf[2 * N + n];
        float qq = __fadd_rn(__fadd_rn(__fmul_rn(qx, qx), __fmul_rn(qy, qy)), __fmul_rn(qz, qz));
        float d0 = INFINITY, d1 = INFINITY, d2 = INFINITY;
        int i0 = 0x7fffffff, i1 = 0x7fffffff, i2 = 0x7fffffff;
#pragma unroll 8
        for (int jj = 0; jj < cs; ++jj) {
            float4 c = cl[jj];               // same addr all lanes -> LDS broadcast
            int j = j0 + jj;
            float s  = fmaf(qz, c.z, fmaf(qy, c.y, __fmul_rn(qx, c.x)));
            float dd = __fadd_rn(__fsub_rn(qq, 2.f * s), c.w);
            // top-3 insert. For sorted d0<=d1<=d2 the select chain equals:
            //   d0' = min(dd,d0); d1' = med3(d0,d1,dd); d2' = med3(d1,d2,dd)
            // (dd<d0 -> {dd,d0,d1}; d0<=dd<d1 -> {d0,dd,d1}; d1<=dd<d2 -> {..,dd};
            //  dd>=d2 -> unchanged) — bit-identical to the a0/a1/a2 version.
            bool a0 = dd < d0, a1 = dd < d1, a2 = dd < d2;
            float nd0 = fminf(dd, d0);
            float nd1 = __builtin_amdgcn_fmed3f(d0, d1, dd);
            float nd2 = __builtin_amdgcn_fmed3f(d1, d2, dd);
            i2 = a1 ? i1 : (a2 ? j : i2);
            i1 = a0 ? i0 : (a1 ? j : i1);
            i0 = a0 ? j : i0;
            d0 = nd0; d1 = nd1; d2 = nd2;
        }
        size_t base = (size_t)(ch * 3) * N + n;
        candd[base] = d0; candd[base + N] = d1; candd[base + 2 * (size_t)N] = d2;
        candi[base] = i0; candi[base + N] = i1; candi[base + 2 * (size_t)N] = i2;
    }
}

// ---------- kernel 2: merge blocks first, then tr_ff blocks (independent) ----------
// NOTE: candd/candi alias d1h (NOT xbuf) so tr_ff's xbuf writes cannot race merge's reads.
__global__ __launch_bounds__(256) void merge_trff_kernel(
    const float* __restrict__ candd, const int* __restrict__ candi,
    const float* __restrict__ xyzf, const float* __restrict__ xyzc,
    const float* __restrict__ ff, unsigned short* __restrict__ xbuf,
    int* __restrict__ idx3, float* __restrict__ w3,
    int N, int M, int Cin, int Cc, int nMerge, int Nb) {
    __shared__ float t[64][65];
    int b = blockIdx.x, tid = threadIdx.x;
    if (b < nMerge) {
        int n = b * 256 + tid;
        float bd0 = INFINITY, bd1 = INFINITY, bd2 = INFINITY;
        int bi0 = 0x7fffffff, bi1 = 0x7fffffff, bi2 = 0x7fffffff;
#pragma unroll
        for (int g = 0; g < (KCH * 3) / 8; ++g) {
            float dd[8]; int ii[8];
#pragma unroll
            for (int e = 0; e < 8; ++e) {
                size_t off = (size_t)(g * 8 + e) * N + n;
                dd[e] = candd[off];
                ii[e] = candi[off];
            }
#pragma unroll
            for (int e = 0; e < 8; ++e) {
                float d = dd[e]; int i = ii[e];
                if (d < bd2 || (d == bd2 && i < bi2)) {
                    if (d < bd1 || (d == bd1 && i < bi1)) {
                        bd2 = bd1; bi2 = bi1;
                        if (d < bd0 || (d == bd0 && i < bi0)) { bd1 = bd0; bi1 = bi0; bd0 = d; bi0 = i; }
                        else                                  { bd1 = d; bi1 = i; }
                    } else { bd2 = d; bi2 = i; }
                }
            }
        }
        float qx = xyzf[n], qy = xyzf[N + n], qz = xyzf[2 * N + n];
        int iif[3] = {bi0, bi1, bi2};
        float u[3];
#pragma unroll
        for (int s = 0; s < 3; ++s) {
            int i = iif[s];
            float cx = xyzc[i], cy = xyzc[M + i], cz = xyzc[2 * M + i];
            float dx = __fsub_rn(qx, cx), dy = __fsub_rn(qy, cy), dz = __fsub_rn(qz, cz);
            float dd = __fadd_rn(__fadd_rn(__fmul_rn(dx, dx), __fmul_rn(dy, dy)), __fmul_rn(dz, dz));
            float dist = fmaxf(sqrtf(dd), 1e-8f);
            u[s] = 1.f / dist;
        }
        float su = __fadd_rn(__fadd_rn(u[0], u[1]), u[2]);
#pragma unroll
        for (int s = 0; s < 3; ++s) {
            idx3[n * 3 + s] = iif[s];
            w3[n * 3 + s] = u[s] / su;
        }
    } else {
        int b2 = b - nMerge;
        int nb = b2 % Nb, cb = b2 / Nb;
        int n0 = nb * 64, c0 = cb * 64;
        int tx = tid & 63, ty = tid >> 6;
#pragma unroll
        for (int i = 0; i < 16; ++i)
            t[ty + 4 * i][tx] = ff[(size_t)(c0 + ty + 4 * i) * N + n0 + tx];
        __syncthreads();
#pragma unroll
        for (int i = 0; i < 16; ++i)
            xbuf[(size_t)(n0 + ty + 4 * i) * Cin + Cc + c0 + tx] = f2bf(t[tx][ty + 4 * i]);
    }
}

// ---------- interp: xbuf[n][c] = sum_s w_s * fcT[i_s][c], c in [0,Cc) ----------
__global__ __launch_bounds__(256) void interp_kernel(
    const unsigned short* __restrict__ fcT, const int* __restrict__ idx3,
    const float* __restrict__ w3, unsigned short* __restrict__ xbuf,
    int Cin, int Cc, int cxB) {
    int b = blockIdx.x, tid = threadIdx.x;
    int cx = b % cxB, n = b / cxB;
    int c = cx * 256 + tid;
    int i0 = idx3[n * 3], i1 = idx3[n * 3 + 1], i2 = idx3[n * 3 + 2];
    float w0 = w3[n * 3], w1 = w3[n * 3 + 1], w2 = w3[n * 3 + 2];
    float f0 = bf2f(fcT[(size_t)i0 * Cc + c]);
    float f1 = bf2f(fcT[(size_t)i1 * Cc + c]);
    float f2_ = bf2f(fcT[(size_t)i2 * Cc + c]);
    float v = fmaf(w2, f2_, fmaf(w1, f1, w0 * f0));
    xbuf[(size_t)n * Cin + c] = f2bf(v);
}

// ---------- bf16 MFMA GEMM (BK=64, two 32-wide panels) -> bf16 D + channel partials ----------
// Panel layout keeps the proven [rows][32] bank pattern; MFMA order identical to BK=32.
__global__ __launch_bounds__(256) void gemm_bf16_kernel(
    const unsigned short* __restrict__ A,  // [O][K] bf16
    const unsigned short* __restrict__ B,  // [Ntot][K] bf16
    unsigned short* __restrict__ Dh,       // [O][Ntot] bf16 (pre-BN activations)
    float* __restrict__ psumG,             // [Ntot/128][O]
    float* __restrict__ psqG,              // [Ntot/128][O]
    int K, int Ntot, int O) {
    __shared__ short As[2 * 128 * 32], Bs[2 * 128 * 32];   // 2 panels x [128][32] each
    int tid = threadIdx.x;
    int lane = tid & 63, wid = tid >> 6;
    int wm = wid & 1, wn = wid >> 1;
    int o0 = blockIdx.y * 128, n0 = blockIdx.x * 128;
    int r16 = lane & 15, kg = lane >> 4;
    float4v acc[4][4];
#pragma unroll
    for (int a = 0; a < 4; ++a)
#pragma unroll
        for (int b = 0; b < 4; ++b)
            acc[a][b] = (float4v){0.f, 0.f, 0.f, 0.f};
    for (int k0 = 0; k0 < K; k0 += 64) {
        // 1024 16B-chunks per matrix per K-step: ch = panel*512 + row*4 + kq
#pragma unroll
        for (int h = 0; h < 4; ++h) {
            int ch = tid + h * 256;
            int panel = ch >> 9, within = ch & 511;
            int row = within >> 2, kq = within & 3;
            int koff = k0 + panel * 32 + kq * 8;
            __builtin_amdgcn_global_load_lds(
                (const __attribute__((address_space(1))) void*)(A + (size_t)(o0 + row) * K + koff),
                (__attribute__((address_space(3))) void*)&As[ch * 8], 16, 0, 0);
            __builtin_amdgcn_global_load_lds(
                (const __attribute__((address_space(1))) void*)(B + (size_t)(n0 + row) * K + koff),
                (__attribute__((address_space(3))) void*)&Bs[ch * 8], 16, 0, 0);
        }
        __syncthreads();
#pragma unroll
        for (int kkp = 0; kkp < 2; ++kkp) {
            short8 af[4], bfr[4];
#pragma unroll
            for (int mi = 0; mi < 4; ++mi)
                af[mi] = *(const short8*)(const void*)&As[kkp * 4096 + (wm * 64 + mi * 16 + r16) * 32 + kg * 8];
#pragma unroll
            for (int ni = 0; ni < 4; ++ni)
                bfr[ni] = *(const short8*)(const void*)&Bs[kkp * 4096 + (wn * 64 + ni * 16 + r16) * 32 + kg * 8];
#pragma unroll
            for (int mi = 0; mi < 4; ++mi)
#pragma unroll
                for (int ni = 0; ni < 4; ++ni)
                    acc[mi][ni] = __builtin_amdgcn_mfma_f32_16x16x32_bf16(af[mi], bfr[ni], acc[mi][ni], 0, 0, 0);
        }
        __syncthreads();
    }
#pragma unroll
    for (int mi = 0; mi < 4; ++mi) {
        int obase = o0 + wm * 64 + mi * 16 + kg * 4;
#pragma unroll
        for (int ni = 0; ni < 4; ++ni) {
            int col = n0 + wn * 64 + ni * 16 + r16;
#pragma unroll
            for (int r = 0; r < 4; ++r)
                Dh[(size_t)(obase + r) * Ntot + col] = f2bf(acc[mi][ni][r]);
        }
    }
    float2* red = (float2*)As;
#pragma unroll
    for (int mi = 0; mi < 4; ++mi) {
#pragma unroll
        for (int r = 0; r < 4; ++r) {
            float s = 0.f, q = 0.f;
#pragma unroll
            for (int ni = 0; ni < 4; ++ni) {
                float v = acc[mi][ni][r];
                s += v; q += v * v;
            }
#pragma unroll
            for (int off = 1; off <= 8; off <<= 1) {
                s += __shfl_xor(s, off);
                q += __shfl_xor(q, off);
            }
            if (r16 == 0) {
                int row = wm * 64 + mi * 16 + kg * 4 + r;
                red[row * 2 + wn] = make_float2(s, q);
            }
        }
    }
    __syncthreads();
    if (tid < 128) {
        float2 a = red[tid * 2 + 0], b = red[tid * 2 + 1];
        int o = o0 + tid;
        psumG[(size_t)blockIdx.x * O + o] = a.x + b.x;
        psqG [(size_t)blockIdx.x * O + o] = a.y + b.y;
    }
}

// ---------- layer1 apply: stats-reduce + BN + ReLU + transpose bf16 [O][N] -> [N][C] ----------
__global__ __launch_bounds__(256) void bnrelu_tr_kernel(
    const unsigned short* __restrict__ Dh, const float* __restrict__ psumG, const float* __restrict__ psqG,
    const float* __restrict__ g, const float* __restrict__ b,
    unsigned short* __restrict__ Z, int Nn, int C, int NB) {
    __shared__ float t[64][65];
    __shared__ float2 st[4][64];
    __shared__ float2 msr[64];
    int tid = threadIdx.x;
    int tx = tid & 63, ty = tid >> 6;
    int n0 = blockIdx.x * 64, o0 = blockIdx.y * 64;
    {
        int ch = tid & 63, q4 = tid >> 6;
        float s = 0.f, qq = 0.f;
        int per = NB / 4;
        for (int i = 0; i < per; ++i) {
            int bx = q4 * per + i;
            s  += psumG[(size_t)bx * C + o0 + ch];
            qq += psqG [(size_t)bx * C + o0 + ch];
        }
        st[q4][ch] = make_float2(s, qq);
    }
#pragma unroll
    for (int i = 0; i < 16; ++i)
        t[ty + 4 * i][tx] = bf2f(Dh[(size_t)(o0 + ty + 4 * i) * Nn + n0 + tx]);
    __syncthreads();
    if (tid < 64) {
        float2 a = st[0][tid], b2 = st[1][tid], c2 = st[2][tid], d2 = st[3][tid];
        float S = (a.x + b2.x) + (c2.x + d2.x);
        float Q = (a.y + b2.y) + (c2.y + d2.y);
        float m = S / Nn;
        float v = Q / Nn - m * m;
        msr[tid] = make_float2(m, rsqrtf(v + 1e-5f));
    }
    __syncthreads();
    int o = o0 + tx;
    float mm = msr[tx].x, rr = msr[tx].y, gg = g[o], bb = b[o];
#pragma unroll
    for (int i = 0; i < 16; ++i) {
        float v = t[tx][ty + 4 * i];
        v = gg * (v - mm) * rr + bb;
        v = fmaxf(v, 0.f);
        Z[(size_t)(n0 + ty + 4 * i) * C + o] = f2bf(v);
    }
}

// ---------- layer2 apply: stats-reduce + BN + ReLU; bf16 D -> f32 out ----------
__global__ __launch_bounds__(256) void bnrelu2_kernel(
    const unsigned short* __restrict__ Dh, float* __restrict__ Y,
    const float* __restrict__ psumG, const float* __restrict__ psqG,
    const float* __restrict__ g, const float* __restrict__ b, int Nn, int C, int NB) {
    __shared__ float2 red[128];
    __shared__ float2 ms;
    int c = blockIdx.y, tid = threadIdx.x;
    if (tid < NB)
        red[tid] = make_float2(psumG[(size_t)tid * C + c], psqG[(size_t)tid * C + c]);
    __syncthreads();
    for (int s2 = NB / 2; s2 > 0; s2 >>= 1) {
        if (tid < s2) {
            red[tid].x += red[tid + s2].x;
            red[tid].y += red[tid + s2].y;
        }
        __syncthreads();
    }
    if (tid == 0) {
        float m = red[0].x / Nn;
        ms = make_float2(m, rsqrtf(red[0].y / Nn - m * m + 1e-5f));
    }
    __syncthreads();
    float mm = ms.x, rr = ms.y, gg = g[c], bb = b[c];
    int q = (int)blockIdx.x * 256 + tid;
    ushort4 dv = ((const ushort4*)(Dh + (size_t)c * Nn))[q];
    float4 v;
    v.x = fmaxf(gg * (bf2f(dv.x) - mm) * rr + bb, 0.f);
    v.y = fmaxf(gg * (bf2f(dv.y) - mm) * rr + bb, 0.f);
    v.z = fmaxf(gg * (bf2f(dv.z) - mm) * rr + bb, 0.f);
    v.w = fmaxf(gg * (bf2f(dv.w) - mm) * rr + bb, 0.f);
    ((float4*)Y)[(size_t)c * (Nn >> 2) + q] = v;
}

extern "C" void kernel_launch(void* const* d_in, const int* in_sizes, int n_in,
                              void* d_out, int out_size, void* d_ws, size_t ws_size,
                              hipStream_t stream) {
    const float* xyzf = (const float*)d_in[0];
    const float* xyzc = (const float*)d_in[1];
    const float* ff   = (const float*)d_in[2];
    const float* fc   = (const float*)d_in[3];
    const float* W1   = (const float*)d_in[4];
    const float* g1   = (const float*)d_in[5];
    const float* b1   = (const float*)d_in[6];
    const float* W2   = (const float*)d_in[7];
    const float* g2   = (const float*)d_in[8];
    const float* b2   = (const float*)d_in[9];

    int N  = in_sizes[0] / 3;       // 16384
    int M  = in_sizes[1] / 3;       // 4096
    int Cf = in_sizes[2] / N;       // 256
    int Cc = in_sizes[3] / M;       // 512
    int h1 = in_sizes[5];           // 512
    int h2 = in_sizes[8];           // 512
    int Cin = Cc + Cf;              // 768
    float* out = (float*)d_out;

    // workspace carve (~48 MB)
    char* p = (char*)d_ws;
    unsigned short* W1h = (unsigned short*)p; p += (size_t)h1 * Cin * 2;
    unsigned short* W2h = (unsigned short*)p; p += (size_t)h2 * h1 * 2;
    unsigned short* fcT = (unsigned short*)p; p += (size_t)M * Cc * 2;
    int*   idx3 = (int*)p;   p += (size_t)N * 3 * sizeof(int);
    float* w3   = (float*)p; p += (size_t)N * 3 * sizeof(float);
    int NB = N / 128;                                   // 128 GEMM n-blocks
    float* psumG = (float*)p; p += (size_t)NB * h1 * sizeof(float);
    float* psqG  = (float*)p; p += (size_t)NB * h1 * sizeof(float);
    unsigned short* d1h = (unsigned short*)p; p += (size_t)h1 * N * 2;   // bf16 pre-BN D
    unsigned short* xbuf = (unsigned short*)p; p += (size_t)N * Cin * 2;
    // cand aliases live in d1h (dead until gemm1) — NOT xbuf, since kernel 2's
    // tr_ff blocks write xbuf concurrently with merge blocks reading cand.
    float* candd = (float*)d1h;                         // [KCH*3][N] = 6.29 MB
    int*   candi = (int*)((char*)d1h + (size_t)KCH * 3 * N * sizeof(float));  // + 6.29 MB <= 16.78 MB
    unsigned short* y2 = xbuf;                          // [N][h1] bf16, alias after GEMM1

    // 1. prologue + kNN scan (independent work fused; prologue blocks first)
    int nW1 = h1 * Cin / 1024, nW2 = h2 * h1 / 1024;
    int Mb = M / 64, nTR = Mb * (Cc / 64);
    int nPro = nW1 + nW2 + nTR;
    scan_pro_kernel<<<nPro + (N / 256) * KCH, 256, 0, stream>>>(
        W1, W2, W1h, W2h, fc, fcT, xyzf, xyzc, candd, candi,
        N, M, Cc, nW1, nW2, nTR, Mb);

    // 2. merge + tr_ff (independent; merge blocks first)
    int nMerge = N / 256, Nb = N / 64, nTF = Nb * (Cf / 64);
    merge_trff_kernel<<<nMerge + nTF, 256, 0, stream>>>(
        candd, candi, xyzf, xyzc, ff, xbuf, idx3, w3, N, M, Cin, Cc, nMerge, Nb);

    // 3. interp
    int cxB = Cc / 256;
    interp_kernel<<<cxB * N, 256, 0, stream>>>(fcT, idx3, w3, xbuf, Cin, Cc, cxB);

    // 4-5. layer 1
    gemm_bf16_kernel<<<dim3(N / 128, h1 / 128), 256, 0, stream>>>(
        W1h, xbuf, d1h, psumG, psqG, Cin, N, h1);
    bnrelu_tr_kernel<<<dim3(N / 64, h1 / 64), 256, 0, stream>>>(
        d1h, psumG, psqG, g1, b1, y2, N, h1, NB);

    // 6-7. layer 2
    gemm_bf16_kernel<<<dim3(N / 128, h2 / 128), 256, 0, stream>>>(
        W2h, y2, d1h, psumG, psqG, h1, N, h2);
    bnrelu2_kernel<<<dim3(N / 1024, h2), 256, 0, stream>>>(
        d1h, out, psumG, psqG, g2, b2, N, h2, NB);
}

// Round 18
// 142.936 us; speedup vs baseline: 1.1622x; 1.0311x over previous
//
#include <hip/hip_runtime.h>
#include <math.h>

typedef __attribute__((ext_vector_type(8))) short short8;
typedef __attribute__((ext_vector_type(4))) float float4v;

__device__ __forceinline__ unsigned short f2bf(float f) {
    unsigned int u = __builtin_bit_cast(unsigned int, f);
    u += 0x7fffu + ((u >> 16) & 1u);
    return (unsigned short)(u >> 16);
}
__device__ __forceinline__ float bf2f(unsigned short h) {
    unsigned int u = ((unsigned int)h) << 16;
    return __builtin_bit_cast(float, u);
}

#define KCH 32

// ---------- kernel 1: prologue (castW1|castW2|tr_fc) blocks, then scan blocks ----------
__global__ __launch_bounds__(256) void scan_pro_kernel(
    const float* __restrict__ W1, const float* __restrict__ W2,
    unsigned short* __restrict__ W1h, unsigned short* __restrict__ W2h,
    const float* __restrict__ fc, unsigned short* __restrict__ fcT,
    const float* __restrict__ xyzf, const float* __restrict__ xyzc,
    float* __restrict__ candd, int* __restrict__ candi,
    int N, int M, int Cc, int nW1, int nW2, int nTR, int Mb) {
    __shared__ float4 smem4[1040];           // 16640 B: tr_fc tile or scan candidates
    int b = blockIdx.x, tid = threadIdx.x;
    int nPro = nW1 + nW2 + nTR;
    if (b < nW1) {
        int q = b * 256 + tid;
        float4 v = ((const float4*)W1)[q];
        ushort4 o; o.x = f2bf(v.x); o.y = f2bf(v.y); o.z = f2bf(v.z); o.w = f2bf(v.w);
        ((ushort4*)W1h)[q] = o;
    } else if (b < nW1 + nW2) {
        int q = (b - nW1) * 256 + tid;
        float4 v = ((const float4*)W2)[q];
        ushort4 o; o.x = f2bf(v.x); o.y = f2bf(v.y); o.z = f2bf(v.z); o.w = f2bf(v.w);
        ((ushort4*)W2h)[q] = o;
    } else if (b < nPro) {
        float (*t)[65] = (float(*)[65])smem4;
        int b2 = b - nW1 - nW2;
        int jb = b2 % Mb, cb = b2 / Mb;
        int j0 = jb * 64, c0 = cb * 64;
        int tx = tid & 63, ty = tid >> 6;
#pragma unroll
        for (int i = 0; i < 16; ++i)
            t[ty + 4 * i][tx] = fc[(size_t)(c0 + ty + 4 * i) * M + j0 + tx];
        __syncthreads();
#pragma unroll
        for (int i = 0; i < 16; ++i)
            fcT[(size_t)(j0 + ty + 4 * i) * Cc + c0 + tx] = f2bf(t[tx][ty + 4 * i]);
    } else {
        // ---- kNN scan: LDS-staged candidates (broadcast reads), min/med3 top-3 ----
        float4* cl = smem4;                  // first 2 KB
        int b2 = b - nPro;
        int n = (b2 & 63) * 256 + tid;       // 64 n-blocks
        int ch = b2 >> 6;                    // KCH chunks
        int cs = M / KCH;                    // 128
        int j0 = ch * cs;
        if (tid < cs) {
            int j = j0 + tid;
            float cx = xyzc[j], cy = xyzc[M + j], cz = xyzc[2 * M + j];
            float cc = __fadd_rn(__fadd_rn(__fmul_rn(cx, cx), __fmul_rn(cy, cy)), __fmul_rn(cz, cz));
            cl[tid] = make_float4(cx, cy, cz, cc);
        }
        __syncthreads();
        float qx = xyzf[n], qy = xyzf[N + n], qz = xyzf[2 * N + n];
        float qq = __fadd_rn(__fadd_rn(__fmul_rn(qx, qx), __fmul_rn(qy, qy)), __fmul_rn(qz, qz));
        float d0 = INFINITY, d1 = INFINITY, d2 = INFINITY;
        int i0 = 0x7fffffff, i1 = 0x7fffffff, i2 = 0x7fffffff;
#pragma unroll 8
        for (int jj = 0; jj < cs; ++jj) {
            float4 c = cl[jj];               // same addr all lanes -> LDS broadcast
            int j = j0 + jj;
            float s  = fmaf(qz, c.z, fmaf(qy, c.y, __fmul_rn(qx, c.x)));
            float dd = __fadd_rn(__fsub_rn(qq, 2.f * s), c.w);
            bool a0 = dd < d0, a1 = dd < d1, a2 = dd < d2;
            float nd0 = fminf(dd, d0);
            float nd1 = __builtin_amdgcn_fmed3f(d0, d1, dd);
            float nd2 = __builtin_amdgcn_fmed3f(d1, d2, dd);
            i2 = a1 ? i1 : (a2 ? j : i2);
            i1 = a0 ? i0 : (a1 ? j : i1);
            i0 = a0 ? j : i0;
            d0 = nd0; d1 = nd1; d2 = nd2;
        }
        size_t base = (size_t)(ch * 3) * N + n;
        candd[base] = d0; candd[base + N] = d1; candd[base + 2 * (size_t)N] = d2;
        candi[base] = i0; candi[base + N] = i1; candi[base + 2 * (size_t)N] = i2;
    }
}

// ---------- kernel 2: merge blocks first, then tr_ff blocks (independent) ----------
__global__ __launch_bounds__(256) void merge_trff_kernel(
    const float* __restrict__ candd, const int* __restrict__ candi,
    const float* __restrict__ xyzf, const float* __restrict__ xyzc,
    const float* __restrict__ ff, unsigned short* __restrict__ xbuf,
    int* __restrict__ idx3, float* __restrict__ w3,
    int N, int M, int Cin, int Cc, int nMerge, int Nb) {
    __shared__ float t[64][65];
    int b = blockIdx.x, tid = threadIdx.x;
    if (b < nMerge) {
        int n = b * 256 + tid;
        float bd0 = INFINITY, bd1 = INFINITY, bd2 = INFINITY;
        int bi0 = 0x7fffffff, bi1 = 0x7fffffff, bi2 = 0x7fffffff;
#pragma unroll
        for (int g = 0; g < (KCH * 3) / 8; ++g) {
            float dd[8]; int ii[8];
#pragma unroll
            for (int e = 0; e < 8; ++e) {
                size_t off = (size_t)(g * 8 + e) * N + n;
                dd[e] = candd[off];
                ii[e] = candi[off];
            }
#pragma unroll
            for (int e = 0; e < 8; ++e) {
                float d = dd[e]; int i = ii[e];
                if (d < bd2 || (d == bd2 && i < bi2)) {
                    if (d < bd1 || (d == bd1 && i < bi1)) {
                        bd2 = bd1; bi2 = bi1;
                        if (d < bd0 || (d == bd0 && i < bi0)) { bd1 = bd0; bi1 = bi0; bd0 = d; bi0 = i; }
                        else                                  { bd1 = d; bi1 = i; }
                    } else { bd2 = d; bi2 = i; }
                }
            }
        }
        float qx = xyzf[n], qy = xyzf[N + n], qz = xyzf[2 * N + n];
        int iif[3] = {bi0, bi1, bi2};
        float u[3];
#pragma unroll
        for (int s = 0; s < 3; ++s) {
            int i = iif[s];
            float cx = xyzc[i], cy = xyzc[M + i], cz = xyzc[2 * M + i];
            float dx = __fsub_rn(qx, cx), dy = __fsub_rn(qy, cy), dz = __fsub_rn(qz, cz);
            float dd = __fadd_rn(__fadd_rn(__fmul_rn(dx, dx), __fmul_rn(dy, dy)), __fmul_rn(dz, dz));
            float dist = fmaxf(sqrtf(dd), 1e-8f);
            u[s] = 1.f / dist;
        }
        float su = __fadd_rn(__fadd_rn(u[0], u[1]), u[2]);
#pragma unroll
        for (int s = 0; s < 3; ++s) {
            idx3[n * 3 + s] = iif[s];
            w3[n * 3 + s] = u[s] / su;
        }
    } else {
        int b2 = b - nMerge;
        int nb = b2 % Nb, cb = b2 / Nb;
        int n0 = nb * 64, c0 = cb * 64;
        int tx = tid & 63, ty = tid >> 6;
#pragma unroll
        for (int i = 0; i < 16; ++i)
            t[ty + 4 * i][tx] = ff[(size_t)(c0 + ty + 4 * i) * N + n0 + tx];
        __syncthreads();
#pragma unroll
        for (int i = 0; i < 16; ++i)
            xbuf[(size_t)(n0 + ty + 4 * i) * Cin + Cc + c0 + tx] = f2bf(t[tx][ty + 4 * i]);
    }
}

// ---------- interp: xbuf[n][c] = sum_s w_s * fcT[i_s][c], c in [0,Cc) ----------
__global__ __launch_bounds__(256) void interp_kernel(
    const unsigned short* __restrict__ fcT, const int* __restrict__ idx3,
    const float* __restrict__ w3, unsigned short* __restrict__ xbuf,
    int Cin, int Cc, int cxB) {
    int b = blockIdx.x, tid = threadIdx.x;
    int cx = b % cxB, n = b / cxB;
    int c = cx * 256 + tid;
    int i0 = idx3[n * 3], i1 = idx3[n * 3 + 1], i2 = idx3[n * 3 + 2];
    float w0 = w3[n * 3], w1 = w3[n * 3 + 1], w2 = w3[n * 3 + 2];
    float f0 = bf2f(fcT[(size_t)i0 * Cc + c]);
    float f1 = bf2f(fcT[(size_t)i1 * Cc + c]);
    float f2_ = bf2f(fcT[(size_t)i2 * Cc + c]);
    float v = fmaf(w2, f2_, fmaf(w1, f1, w0 * f0));
    xbuf[(size_t)n * Cin + c] = f2bf(v);
}

// ---------- bf16 MFMA GEMM (BK=128, four 32-wide panels) + channel partials ----------
// TRANS=1: write D packed-transposed to Dt[n][O] (ushort4); TRANS=0: Dt[o][Ntot] scalar.
template <int TRANS>
__global__ __launch_bounds__(256) void gemm_bf16_kernel(
    const unsigned short* __restrict__ A,  // [O][K] bf16
    const unsigned short* __restrict__ B,  // [Ntot][K] bf16
    unsigned short* __restrict__ Dt,       // TRANS? [Ntot][O] : [O][Ntot]
    float* __restrict__ psumG,             // [Ntot/128][O]
    float* __restrict__ psqG,              // [Ntot/128][O]
    int K, int Ntot, int O) {
    __shared__ short As[4 * 128 * 32], Bs[4 * 128 * 32];   // 4 panels x [128][32], 64 KB
    int tid = threadIdx.x;
    int lane = tid & 63, wid = tid >> 6;
    int wm = wid & 1, wn = wid >> 1;
    int o0 = blockIdx.y * 128, n0 = blockIdx.x * 128;
    int r16 = lane & 15, kg = lane >> 4;
    float4v acc[4][4];
#pragma unroll
    for (int a = 0; a < 4; ++a)
#pragma unroll
        for (int b = 0; b < 4; ++b)
            acc[a][b] = (float4v){0.f, 0.f, 0.f, 0.f};
    for (int k0 = 0; k0 < K; k0 += 128) {
        // 2048 16B-chunks per matrix per K-step: ch = panel*512 + row*4 + kq
#pragma unroll
        for (int h = 0; h < 8; ++h) {
            int ch = tid + h * 256;
            int panel = ch >> 9, within = ch & 511;
            int row = within >> 2, kq = within & 3;
            int koff = k0 + panel * 32 + kq * 8;
            __builtin_amdgcn_global_load_lds(
                (const __attribute__((address_space(1))) void*)(A + (size_t)(o0 + row) * K + koff),
                (__attribute__((address_space(3))) void*)&As[ch * 8], 16, 0, 0);
            __builtin_amdgcn_global_load_lds(
                (const __attribute__((address_space(1))) void*)(B + (size_t)(n0 + row) * K + koff),
                (__attribute__((address_space(3))) void*)&Bs[ch * 8], 16, 0, 0);
        }
        __syncthreads();
#pragma unroll
        for (int kkp = 0; kkp < 4; ++kkp) {
            short8 af[4], bfr[4];
#pragma unroll
            for (int mi = 0; mi < 4; ++mi)
                af[mi] = *(const short8*)(const void*)&As[kkp * 4096 + (wm * 64 + mi * 16 + r16) * 32 + kg * 8];
#pragma unroll
            for (int ni = 0; ni < 4; ++ni)
                bfr[ni] = *(const short8*)(const void*)&Bs[kkp * 4096 + (wn * 64 + ni * 16 + r16) * 32 + kg * 8];
#pragma unroll
            for (int mi = 0; mi < 4; ++mi)
#pragma unroll
                for (int ni = 0; ni < 4; ++ni)
                    acc[mi][ni] = __builtin_amdgcn_mfma_f32_16x16x32_bf16(af[mi], bfr[ni], acc[mi][ni], 0, 0, 0);
        }
        __syncthreads();
    }
    if (TRANS) {
        // packed write: Dt[n][obase..obase+3] as one ushort4
#pragma unroll
        for (int mi = 0; mi < 4; ++mi) {
            int obase = o0 + wm * 64 + mi * 16 + kg * 4;
#pragma unroll
            for (int ni = 0; ni < 4; ++ni) {
                int n = n0 + wn * 64 + ni * 16 + r16;
                ushort4 pk;
                pk.x = f2bf(acc[mi][ni][0]);
                pk.y = f2bf(acc[mi][ni][1]);
                pk.z = f2bf(acc[mi][ni][2]);
                pk.w = f2bf(acc[mi][ni][3]);
                *(ushort4*)(void*)&Dt[(size_t)n * O + obase] = pk;
            }
        }
    } else {
#pragma unroll
        for (int mi = 0; mi < 4; ++mi) {
            int obase = o0 + wm * 64 + mi * 16 + kg * 4;
#pragma unroll
            for (int ni = 0; ni < 4; ++ni) {
                int col = n0 + wn * 64 + ni * 16 + r16;
#pragma unroll
                for (int r = 0; r < 4; ++r)
                    Dt[(size_t)(obase + r) * Ntot + col] = f2bf(acc[mi][ni][r]);
            }
        }
    }
    float2* red = (float2*)As;
#pragma unroll
    for (int mi = 0; mi < 4; ++mi) {
#pragma unroll
        for (int r = 0; r < 4; ++r) {
            float s = 0.f, q = 0.f;
#pragma unroll
            for (int ni = 0; ni < 4; ++ni) {
                float v = acc[mi][ni][r];
                s += v; q += v * v;
            }
#pragma unroll
            for (int off = 1; off <= 8; off <<= 1) {
                s += __shfl_xor(s, off);
                q += __shfl_xor(q, off);
            }
            if (r16 == 0) {
                int row = wm * 64 + mi * 16 + kg * 4 + r;
                red[row * 2 + wn] = make_float2(s, q);
            }
        }
    }
    __syncthreads();
    if (tid < 128) {
        float2 a = red[tid * 2 + 0], b = red[tid * 2 + 1];
        int o = o0 + tid;
        psumG[(size_t)blockIdx.x * O + o] = a.x + b.x;
        psqG [(size_t)blockIdx.x * O + o] = a.y + b.y;
    }
}

// ---------- layer1 apply: stats-reduce + BN + ReLU in place on y[N][C] bf16 ----------
__global__ __launch_bounds__(256) void bnrelu_ip_kernel(
    unsigned short* __restrict__ Y, const float* __restrict__ psumG, const float* __restrict__ psqG,
    const float* __restrict__ g, const float* __restrict__ b, int Nn, int C, int NB) {
    __shared__ float2 st[4][64];
    __shared__ float2 msr[64], gbl[64];
    int tid = threadIdx.x;
    int n0 = blockIdx.x * 64, o0 = blockIdx.y * 64;
    {
        int ch = tid & 63, q4 = tid >> 6;
        float s = 0.f, qq = 0.f;
        int per = NB / 4;
        for (int i = 0; i < per; ++i) {
            int bx = q4 * per + i;
            s  += psumG[(size_t)bx * C + o0 + ch];
            qq += psqG [(size_t)bx * C + o0 + ch];
        }
        st[q4][ch] = make_float2(s, qq);
    }
    __syncthreads();
    if (tid < 64) {
        float2 a = st[0][tid], b2 = st[1][tid], c2 = st[2][tid], d2 = st[3][tid];
        float S = (a.x + b2.x) + (c2.x + d2.x);
        float Q = (a.y + b2.y) + (c2.y + d2.y);
        float m = S / Nn;
        float v = Q / Nn - m * m;
        msr[tid] = make_float2(m, rsqrtf(v + 1e-5f));
        gbl[tid] = make_float2(g[o0 + tid], b[o0 + tid]);
    }
    __syncthreads();
    // 64 rows x 16 ushort4; thread = (row = tid>>2, k0 = tid&3), 4 quads each
    int row = tid >> 2, k0 = tid & 3;
#pragma unroll
    for (int j = 0; j < 4; ++j) {
        int k = k0 + 4 * j;
        size_t a = (size_t)(n0 + row) * C + o0 + k * 4;
        ushort4 v = *(const ushort4*)(const void*)&Y[a];
        int ob = k * 4;
        float2 ms0 = msr[ob], ms1 = msr[ob + 1], ms2 = msr[ob + 2], ms3 = msr[ob + 3];
        float2 gb0 = gbl[ob], gb1 = gbl[ob + 1], gb2 = gbl[ob + 2], gb3 = gbl[ob + 3];
        v.x = f2bf(fmaxf(gb0.x * (bf2f(v.x) - ms0.x) * ms0.y + gb0.y, 0.f));
        v.y = f2bf(fmaxf(gb1.x * (bf2f(v.y) - ms1.x) * ms1.y + gb1.y, 0.f));
        v.z = f2bf(fmaxf(gb2.x * (bf2f(v.z) - ms2.x) * ms2.y + gb2.y, 0.f));
        v.w = f2bf(fmaxf(gb3.x * (bf2f(v.w) - ms3.x) * ms3.y + gb3.y, 0.f));
        *(ushort4*)(void*)&Y[a] = v;
    }
}

// ---------- layer2 apply: stats-reduce + BN + ReLU; bf16 D [O][N] -> f32 out ----------
__global__ __launch_bounds__(256) void bnrelu2_kernel(
    const unsigned short* __restrict__ Dh, float* __restrict__ Y,
    const float* __restrict__ psumG, const float* __restrict__ psqG,
    const float* __restrict__ g, const float* __restrict__ b, int Nn, int C, int NB) {
    __shared__ float2 red[128];
    __shared__ float2 ms;
    int c = blockIdx.y, tid = threadIdx.x;
    if (tid < NB)
        red[tid] = make_float2(psumG[(size_t)tid * C + c], psqG[(size_t)tid * C + c]);
    __syncthreads();
    for (int s2 = NB / 2; s2 > 0; s2 >>= 1) {
        if (tid < s2) {
            red[tid].x += red[tid + s2].x;
            red[tid].y += red[tid + s2].y;
        }
        __syncthreads();
    }
    if (tid == 0) {
        float m = red[0].x / Nn;
        ms = make_float2(m, rsqrtf(red[0].y / Nn - m * m + 1e-5f));
    }
    __syncthreads();
    float mm = ms.x, rr = ms.y, gg = g[c], bb = b[c];
    int q = (int)blockIdx.x * 256 + tid;
    ushort4 dv = ((const ushort4*)(Dh + (size_t)c * Nn))[q];
    float4 v;
    v.x = fmaxf(gg * (bf2f(dv.x) - mm) * rr + bb, 0.f);
    v.y = fmaxf(gg * (bf2f(dv.y) - mm) * rr + bb, 0.f);
    v.z = fmaxf(gg * (bf2f(dv.z) - mm) * rr + bb, 0.f);
    v.w = fmaxf(gg * (bf2f(dv.w) - mm) * rr + bb, 0.f);
    ((float4*)Y)[(size_t)c * (Nn >> 2) + q] = v;
}

extern "C" void kernel_launch(void* const* d_in, const int* in_sizes, int n_in,
                              void* d_out, int out_size, void* d_ws, size_t ws_size,
                              hipStream_t stream) {
    const float* xyzf = (const float*)d_in[0];
    const float* xyzc = (const float*)d_in[1];
    const float* ff   = (const float*)d_in[2];
    const float* fc   = (const float*)d_in[3];
    const float* W1   = (const float*)d_in[4];
    const float* g1   = (const float*)d_in[5];
    const float* b1   = (const float*)d_in[6];
    const float* W2   = (const float*)d_in[7];
    const float* g2   = (const float*)d_in[8];
    const float* b2   = (const float*)d_in[9];

    int N  = in_sizes[0] / 3;       // 16384
    int M  = in_sizes[1] / 3;       // 4096
    int Cf = in_sizes[2] / N;       // 256
    int Cc = in_sizes[3] / M;       // 512
    int h1 = in_sizes[5];           // 512
    int h2 = in_sizes[8];           // 512
    int Cin = Cc + Cf;              // 768
    float* out = (float*)d_out;

    // workspace carve (~48 MB)
    char* p = (char*)d_ws;
    unsigned short* W1h = (unsigned short*)p; p += (size_t)h1 * Cin * 2;
    unsigned short* W2h = (unsigned short*)p; p += (size_t)h2 * h1 * 2;
    unsigned short* fcT = (unsigned short*)p; p += (size_t)M * Cc * 2;
    int*   idx3 = (int*)p;   p += (size_t)N * 3 * sizeof(int);
    float* w3   = (float*)p; p += (size_t)N * 3 * sizeof(float);
    int NB = N / 128;                                   // 128 GEMM n-blocks
    float* psumG = (float*)p; p += (size_t)NB * h1 * sizeof(float);
    float* psqG  = (float*)p; p += (size_t)NB * h1 * sizeof(float);
    unsigned short* d1h = (unsigned short*)p; p += (size_t)h1 * N * 2;   // y-layout [N][h1] bf16
    unsigned short* xbuf = (unsigned short*)p; p += (size_t)N * Cin * 2;
    // cand aliases live in d1h (dead after merge; gemm1 writes d1h later).
    float* candd = (float*)d1h;                         // [KCH*3][N] = 6.29 MB
    int*   candi = (int*)((char*)d1h + (size_t)KCH * 3 * N * sizeof(float));  // + 6.29 MB <= 16.78 MB
    unsigned short* d2h = xbuf;                         // gemm2 D [h2][N] bf16 (xbuf dead post-gemm1)

    // 1. prologue + kNN scan (independent work fused; prologue blocks first)
    int nW1 = h1 * Cin / 1024, nW2 = h2 * h1 / 1024;
    int Mb = M / 64, nTR = Mb * (Cc / 64);
    int nPro = nW1 + nW2 + nTR;
    scan_pro_kernel<<<nPro + (N / 256) * KCH, 256, 0, stream>>>(
        W1, W2, W1h, W2h, fc, fcT, xyzf, xyzc, candd, candi,
        N, M, Cc, nW1, nW2, nTR, Mb);

    // 2. merge + tr_ff (independent; merge blocks first)
    int nMerge = N / 256, Nb = N / 64, nTF = Nb * (Cf / 64);
    merge_trff_kernel<<<nMerge + nTF, 256, 0, stream>>>(
        candd, candi, xyzf, xyzc, ff, xbuf, idx3, w3, N, M, Cin, Cc, nMerge, Nb);

    // 3. interp
    int cxB = Cc / 256;
    interp_kernel<<<cxB * N, 256, 0, stream>>>(fcT, idx3, w3, xbuf, Cin, Cc, cxB);

    // 4-5. layer 1: gemm1 writes y-layout [N][h1] into d1h; bn1 in place
    gemm_bf16_kernel<1><<<dim3(N / 128, h1 / 128), 256, 0, stream>>>(
        W1h, xbuf, d1h, psumG, psqG, Cin, N, h1);
    bnrelu_ip_kernel<<<dim3(N / 64, h1 / 64), 256, 0, stream>>>(
        d1h, psumG, psqG, g1, b1, N, h1, NB);

    // 6-7. layer 2: gemm2 reads d1h as B, writes [h2][N] into xbuf; bn2 -> out
    gemm_bf16_kernel<0><<<dim3(N / 128, h2 / 128), 256, 0, stream>>>(
        W2h, d1h, d2h, psumG, psqG, h1, N, h2);
    bnrelu2_kernel<<<dim3(N / 1024, h2), 256, 0, stream>>>(
        d2h, out, psumG, psqG, g2, b2, N, h2, NB);
}

// Round 19
// 129.990 us; speedup vs baseline: 1.2780x; 1.0996x over previous
//
#include <hip/hip_runtime.h>
#include <math.h>

typedef __attribute__((ext_vector_type(8))) short short8;
typedef __attribute__((ext_vector_type(4))) float float4v;

__device__ __forceinline__ unsigned short f2bf(float f) {
    unsigned int u = __builtin_bit_cast(unsigned int, f);
    u += 0x7fffu + ((u >> 16) & 1u);
    return (unsigned short)(u >> 16);
}
__device__ __forceinline__ float bf2f(unsigned short h) {
    unsigned int u = ((unsigned int)h) << 16;
    return __builtin_bit_cast(float, u);
}
__device__ __forceinline__ float i2f(int i) { return __builtin_bit_cast(float, i); }
__device__ __forceinline__ int f2i(float f) { return __builtin_bit_cast(int, f); }

#define KCH 32

// ---------- kernel 1: prologue (castW1|castW2|tr_fc) blocks, then scan blocks ----------
// cand record layout: [KCH][N][8] floats = {d0,d1,d2,i0,i1,i2,pad,pad} (32B/record)
__global__ __launch_bounds__(256) void scan_pro_kernel(
    const float* __restrict__ W1, const float* __restrict__ W2,
    unsigned short* __restrict__ W1h, unsigned short* __restrict__ W2h,
    const float* __restrict__ fc, unsigned short* __restrict__ fcT,
    const float* __restrict__ xyzf, const float* __restrict__ xyzc,
    float4* __restrict__ cand,             // [KCH][N][2] float4
    int N, int M, int Cc, int nW1, int nW2, int nTR, int Mb) {
    __shared__ float4 smem4[1040];           // 16640 B: tr_fc tile or scan candidates
    int b = blockIdx.x, tid = threadIdx.x;
    int nPro = nW1 + nW2 + nTR;
    if (b < nW1) {
        int q = b * 256 + tid;
        float4 v = ((const float4*)W1)[q];
        ushort4 o; o.x = f2bf(v.x); o.y = f2bf(v.y); o.z = f2bf(v.z); o.w = f2bf(v.w);
        ((ushort4*)W1h)[q] = o;
    } else if (b < nW1 + nW2) {
        int q = (b - nW1) * 256 + tid;
        float4 v = ((const float4*)W2)[q];
        ushort4 o; o.x = f2bf(v.x); o.y = f2bf(v.y); o.z = f2bf(v.z); o.w = f2bf(v.w);
        ((ushort4*)W2h)[q] = o;
    } else if (b < nPro) {
        float (*t)[65] = (float(*)[65])smem4;
        int b2 = b - nW1 - nW2;
        int jb = b2 % Mb, cb = b2 / Mb;
        int j0 = jb * 64, c0 = cb * 64;
        int tx = tid & 63, ty = tid >> 6;
#pragma unroll
        for (int i = 0; i < 16; ++i)
            t[ty + 4 * i][tx] = fc[(size_t)(c0 + ty + 4 * i) * M + j0 + tx];
        __syncthreads();
#pragma unroll
        for (int i = 0; i < 16; ++i)
            fcT[(size_t)(j0 + ty + 4 * i) * Cc + c0 + tx] = f2bf(t[tx][ty + 4 * i]);
    } else {
        // ---- kNN scan: LDS-staged candidates (broadcast reads), min/med3 top-3 ----
        float4* cl = smem4;                  // first 2 KB
        int b2 = b - nPro;
        int n = (b2 & 63) * 256 + tid;       // 64 n-blocks
        int ch = b2 >> 6;                    // KCH chunks
        int cs = M / KCH;                    // 128
        int j0 = ch * cs;
        if (tid < cs) {
            int j = j0 + tid;
            float cx = xyzc[j], cy = xyzc[M + j], cz = xyzc[2 * M + j];
            float cc = __fadd_rn(__fadd_rn(__fmul_rn(cx, cx), __fmul_rn(cy, cy)), __fmul_rn(cz, cz));
            cl[tid] = make_float4(cx, cy, cz, cc);
        }
        __syncthreads();
        float qx = xyzf[n], qy = xyzf[N + n], qz = xyzf[2 * N + n];
        float qq = __fadd_rn(__fadd_rn(__fmul_rn(qx, qx), __fmul_rn(qy, qy)), __fmul_rn(qz, qz));
        float d0 = INFINITY, d1 = INFINITY, d2 = INFINITY;
        int i0 = 0x7fffffff, i1 = 0x7fffffff, i2 = 0x7fffffff;
#pragma unroll 8
        for (int jj = 0; jj < cs; ++jj) {
            float4 c = cl[jj];               // same addr all lanes -> LDS broadcast
            int j = j0 + jj;
            float s  = fmaf(qz, c.z, fmaf(qy, c.y, __fmul_rn(qx, c.x)));
            float dd = __fadd_rn(__fsub_rn(qq, 2.f * s), c.w);
            bool a0 = dd < d0, a1 = dd < d1, a2 = dd < d2;
            float nd0 = fminf(dd, d0);
            float nd1 = __builtin_amdgcn_fmed3f(d0, d1, dd);
            float nd2 = __builtin_amdgcn_fmed3f(d1, d2, dd);
            i2 = a1 ? i1 : (a2 ? j : i2);
            i1 = a0 ? i0 : (a1 ? j : i1);
            i0 = a0 ? j : i0;
            d0 = nd0; d1 = nd1; d2 = nd2;
        }
        size_t rec = ((size_t)ch * N + n) * 2;
        cand[rec]     = make_float4(d0, d1, d2, i2f(i0));
        cand[rec + 1] = make_float4(i2f(i1), i2f(i2), 0.f, 0.f);
    }
}

// ---------- kernel 2: merge blocks first, then tr_ff blocks (independent) ----------
// cand records read as 2 x float4 per chunk (wide loads); entry order identical
// to the old sequential ch*3+slot order, so selection is bit-identical.
__global__ __launch_bounds__(256) void merge_trff_kernel(
    const float4* __restrict__ cand,
    const float* __restrict__ xyzf, const float* __restrict__ xyzc,
    const float* __restrict__ ff, unsigned short* __restrict__ xbuf,
    int* __restrict__ idx3, float* __restrict__ w3,
    int N, int M, int Cin, int Cc, int nMerge, int Nb) {
    __shared__ float t[64][65];
    int b = blockIdx.x, tid = threadIdx.x;
    if (b < nMerge) {
        int n = b * 256 + tid;
        float bd0 = INFINITY, bd1 = INFINITY, bd2 = INFINITY;
        int bi0 = 0x7fffffff, bi1 = 0x7fffffff, bi2 = 0x7fffffff;
#pragma unroll
        for (int chg = 0; chg < KCH / 4; ++chg) {
            float4 ra[4], rb[4];
#pragma unroll
            for (int k = 0; k < 4; ++k) {
                size_t rec = ((size_t)(chg * 4 + k) * N + n) * 2;
                ra[k] = cand[rec];
                rb[k] = cand[rec + 1];
            }
#pragma unroll
            for (int k = 0; k < 4; ++k) {
                float dv[3] = {ra[k].x, ra[k].y, ra[k].z};
                int iv[3] = {f2i(ra[k].w), f2i(rb[k].x), f2i(rb[k].y)};
#pragma unroll
                for (int e = 0; e < 3; ++e) {
                    float d = dv[e]; int i = iv[e];
                    if (d < bd2 || (d == bd2 && i < bi2)) {
                        if (d < bd1 || (d == bd1 && i < bi1)) {
                            bd2 = bd1; bi2 = bi1;
                            if (d < bd0 || (d == bd0 && i < bi0)) { bd1 = bd0; bi1 = bi0; bd0 = d; bi0 = i; }
                            else                                  { bd1 = d; bi1 = i; }
                        } else { bd2 = d; bi2 = i; }
                    }
                }
            }
        }
        float qx = xyzf[n], qy = xyzf[N + n], qz = xyzf[2 * N + n];
        int iif[3] = {bi0, bi1, bi2};
        float u[3];
#pragma unroll
        for (int s = 0; s < 3; ++s) {
            int i = iif[s];
            float cx = xyzc[i], cy = xyzc[M + i], cz = xyzc[2 * M + i];
            float dx = __fsub_rn(qx, cx), dy = __fsub_rn(qy, cy), dz = __fsub_rn(qz, cz);
            float dd = __fadd_rn(__fadd_rn(__fmul_rn(dx, dx), __fmul_rn(dy, dy)), __fmul_rn(dz, dz));
            float dist = fmaxf(sqrtf(dd), 1e-8f);
            u[s] = 1.f / dist;
        }
        float su = __fadd_rn(__fadd_rn(u[0], u[1]), u[2]);
#pragma unroll
        for (int s = 0; s < 3; ++s) {
            idx3[n * 3 + s] = iif[s];
            w3[n * 3 + s] = u[s] / su;
        }
    } else {
        int b2 = b - nMerge;
        int nb = b2 % Nb, cb = b2 / Nb;
        int n0 = nb * 64, c0 = cb * 64;
        int tx = tid & 63, ty = tid >> 6;
#pragma unroll
        for (int i = 0; i < 16; ++i)
            t[ty + 4 * i][tx] = ff[(size_t)(c0 + ty + 4 * i) * N + n0 + tx];
        __syncthreads();
#pragma unroll
        for (int i = 0; i < 16; ++i)
            xbuf[(size_t)(n0 + ty + 4 * i) * Cin + Cc + c0 + tx] = f2bf(t[tx][ty + 4 * i]);
    }
}

// ---------- interp (vectorized 8 ch/thread): xbuf[n][c..c+7] = sum_s w_s*fcT[i_s][c..c+7] ----------
__global__ __launch_bounds__(256) void interp_kernel(
    const unsigned short* __restrict__ fcT, const int* __restrict__ idx3,
    const float* __restrict__ w3, unsigned short* __restrict__ xbuf,
    int Cin, int Cc) {
    int tid = threadIdx.x;
    int ploc = tid >> 6, cs = tid & 63;      // 4 points/block, 64 chan-slots
    int n = blockIdx.x * 4 + ploc;
    int c = cs * 8;
    int i0 = idx3[n * 3], i1 = idx3[n * 3 + 1], i2 = idx3[n * 3 + 2];
    float w0 = w3[n * 3], w1 = w3[n * 3 + 1], w2 = w3[n * 3 + 2];
    short8 f0 = *(const short8*)(const void*)&fcT[(size_t)i0 * Cc + c];
    short8 f1 = *(const short8*)(const void*)&fcT[(size_t)i1 * Cc + c];
    short8 f2v = *(const short8*)(const void*)&fcT[(size_t)i2 * Cc + c];
    short8 o;
#pragma unroll
    for (int j = 0; j < 8; ++j) {
        float a = bf2f((unsigned short)f0[j]);
        float bb = bf2f((unsigned short)f1[j]);
        float cc = bf2f((unsigned short)f2v[j]);
        float v = fmaf(w2, cc, fmaf(w1, bb, w0 * a));
        o[j] = (short)f2bf(v);
    }
    *(short8*)(void*)&xbuf[(size_t)n * Cin + c] = o;
}

// ---------- bf16 MFMA GEMM (BK=128, four 32-wide panels) + channel partials ----------
template <int TRANS>
__global__ __launch_bounds__(256) void gemm_bf16_kernel(
    const unsigned short* __restrict__ A,  // [O][K] bf16
    const unsigned short* __restrict__ B,  // [Ntot][K] bf16
    unsigned short* __restrict__ Dt,       // TRANS? [Ntot][O] : [O][Ntot]
    float* __restrict__ psumG,             // [Ntot/128][O]
    float* __restrict__ psqG,              // [Ntot/128][O]
    int K, int Ntot, int O) {
    __shared__ short As[4 * 128 * 32], Bs[4 * 128 * 32];   // 4 panels x [128][32], 64 KB
    int tid = threadIdx.x;
    int lane = tid & 63, wid = tid >> 6;
    int wm = wid & 1, wn = wid >> 1;
    int o0 = blockIdx.y * 128, n0 = blockIdx.x * 128;
    int r16 = lane & 15, kg = lane >> 4;
    float4v acc[4][4];
#pragma unroll
    for (int a = 0; a < 4; ++a)
#pragma unroll
        for (int b = 0; b < 4; ++b)
            acc[a][b] = (float4v){0.f, 0.f, 0.f, 0.f};
    for (int k0 = 0; k0 < K; k0 += 128) {
#pragma unroll
        for (int h = 0; h < 8; ++h) {
            int ch = tid + h * 256;
            int panel = ch >> 9, within = ch & 511;
            int row = within >> 2, kq = within & 3;
            int koff = k0 + panel * 32 + kq * 8;
            __builtin_amdgcn_global_load_lds(
                (const __attribute__((address_space(1))) void*)(A + (size_t)(o0 + row) * K + koff),
                (__attribute__((address_space(3))) void*)&As[ch * 8], 16, 0, 0);
            __builtin_amdgcn_global_load_lds(
                (const __attribute__((address_space(1))) void*)(B + (size_t)(n0 + row) * K + koff),
                (__attribute__((address_space(3))) void*)&Bs[ch * 8], 16, 0, 0);
        }
        __syncthreads();
#pragma unroll
        for (int kkp = 0; kkp < 4; ++kkp) {
            short8 af[4], bfr[4];
#pragma unroll
            for (int mi = 0; mi < 4; ++mi)
                af[mi] = *(const short8*)(const void*)&As[kkp * 4096 + (wm * 64 + mi * 16 + r16) * 32 + kg * 8];
#pragma unroll
            for (int ni = 0; ni < 4; ++ni)
                bfr[ni] = *(const short8*)(const void*)&Bs[kkp * 4096 + (wn * 64 + ni * 16 + r16) * 32 + kg * 8];
#pragma unroll
            for (int mi = 0; mi < 4; ++mi)
#pragma unroll
                for (int ni = 0; ni < 4; ++ni)
                    acc[mi][ni] = __builtin_amdgcn_mfma_f32_16x16x32_bf16(af[mi], bfr[ni], acc[mi][ni], 0, 0, 0);
        }
        __syncthreads();
    }
    if (TRANS) {
#pragma unroll
        for (int mi = 0; mi < 4; ++mi) {
            int obase = o0 + wm * 64 + mi * 16 + kg * 4;
#pragma unroll
            for (int ni = 0; ni < 4; ++ni) {
                int n = n0 + wn * 64 + ni * 16 + r16;
                ushort4 pk;
                pk.x = f2bf(acc[mi][ni][0]);
                pk.y = f2bf(acc[mi][ni][1]);
                pk.z = f2bf(acc[mi][ni][2]);
                pk.w = f2bf(acc[mi][ni][3]);
                *(ushort4*)(void*)&Dt[(size_t)n * O + obase] = pk;
            }
        }
    } else {
#pragma unroll
        for (int mi = 0; mi < 4; ++mi) {
            int obase = o0 + wm * 64 + mi * 16 + kg * 4;
#pragma unroll
            for (int ni = 0; ni < 4; ++ni) {
                int col = n0 + wn * 64 + ni * 16 + r16;
#pragma unroll
                for (int r = 0; r < 4; ++r)
                    Dt[(size_t)(obase + r) * Ntot + col] = f2bf(acc[mi][ni][r]);
            }
        }
    }
    float2* red = (float2*)As;
#pragma unroll
    for (int mi = 0; mi < 4; ++mi) {
#pragma unroll
        for (int r = 0; r < 4; ++r) {
            float s = 0.f, q = 0.f;
#pragma unroll
            for (int ni = 0; ni < 4; ++ni) {
                float v = acc[mi][ni][r];
                s += v; q += v * v;
            }
#pragma unroll
            for (int off = 1; off <= 8; off <<= 1) {
                s += __shfl_xor(s, off);
                q += __shfl_xor(q, off);
            }
            if (r16 == 0) {
                int row = wm * 64 + mi * 16 + kg * 4 + r;
                red[row * 2 + wn] = make_float2(s, q);
            }
        }
    }
    __syncthreads();
    if (tid < 128) {
        float2 a = red[tid * 2 + 0], b = red[tid * 2 + 1];
        int o = o0 + tid;
        psumG[(size_t)blockIdx.x * O + o] = a.x + b.x;
        psqG [(size_t)blockIdx.x * O + o] = a.y + b.y;
    }
}

// ---------- layer1 apply: stats-reduce + BN + ReLU in place on y[N][C] bf16 ----------
__global__ __launch_bounds__(256) void bnrelu_ip_kernel(
    unsigned short* __restrict__ Y, const float* __restrict__ psumG, const float* __restrict__ psqG,
    const float* __restrict__ g, const float* __restrict__ b, int Nn, int C, int NB) {
    __shared__ float2 st[4][64];
    __shared__ float2 msr[64], gbl[64];
    int tid = threadIdx.x;
    int n0 = blockIdx.x * 64, o0 = blockIdx.y * 64;
    {
        int ch = tid & 63, q4 = tid >> 6;
        float s = 0.f, qq = 0.f;
        int per = NB / 4;
        for (int i = 0; i < per; ++i) {
            int bx = q4 * per + i;
            s  += psumG[(size_t)bx * C + o0 + ch];
            qq += psqG [(size_t)bx * C + o0 + ch];
        }
        st[q4][ch] = make_float2(s, qq);
    }
    __syncthreads();
    if (tid < 64) {
        float2 a = st[0][tid], b2 = st[1][tid], c2 = st[2][tid], d2 = st[3][tid];
        float S = (a.x + b2.x) + (c2.x + d2.x);
        float Q = (a.y + b2.y) + (c2.y + d2.y);
        float m = S / Nn;
        float v = Q / Nn - m * m;
        msr[tid] = make_float2(m, rsqrtf(v + 1e-5f));
        gbl[tid] = make_float2(g[o0 + tid], b[o0 + tid]);
    }
    __syncthreads();
    int row = tid >> 2, k0 = tid & 3;
#pragma unroll
    for (int j = 0; j < 4; ++j) {
        int k = k0 + 4 * j;
        size_t a = (size_t)(n0 + row) * C + o0 + k * 4;
        ushort4 v = *(const ushort4*)(const void*)&Y[a];
        int ob = k * 4;
        float2 ms0 = msr[ob], ms1 = msr[ob + 1], ms2 = msr[ob + 2], ms3 = msr[ob + 3];
        float2 gb0 = gbl[ob], gb1 = gbl[ob + 1], gb2 = gbl[ob + 2], gb3 = gbl[ob + 3];
        v.x = f2bf(fmaxf(gb0.x * (bf2f(v.x) - ms0.x) * ms0.y + gb0.y, 0.f));
        v.y = f2bf(fmaxf(gb1.x * (bf2f(v.y) - ms1.x) * ms1.y + gb1.y, 0.f));
        v.z = f2bf(fmaxf(gb2.x * (bf2f(v.z) - ms2.x) * ms2.y + gb2.y, 0.f));
        v.w = f2bf(fmaxf(gb3.x * (bf2f(v.w) - ms3.x) * ms3.y + gb3.y, 0.f));
        *(ushort4*)(void*)&Y[a] = v;
    }
}

// ---------- layer2 apply: stats-reduce + BN + ReLU; bf16 D [O][N] -> f32 out ----------
__global__ __launch_bounds__(256) void bnrelu2_kernel(
    const unsigned short* __restrict__ Dh, float* __restrict__ Y,
    const float* __restrict__ psumG, const float* __restrict__ psqG,
    const float* __restrict__ g, const float* __restrict__ b, int Nn, int C, int NB) {
    __shared__ float2 red[128];
    __shared__ float2 ms;
    int c = blockIdx.y, tid = threadIdx.x;
    if (tid < NB)
        red[tid] = make_float2(psumG[(size_t)tid * C + c], psqG[(size_t)tid * C + c]);
    __syncthreads();
    for (int s2 = NB / 2; s2 > 0; s2 >>= 1) {
        if (tid < s2) {
            red[tid].x += red[tid + s2].x;
            red[tid].y += red[tid + s2].y;
        }
        __syncthreads();
    }
    if (tid == 0) {
        float m = red[0].x / Nn;
        ms = make_float2(m, rsqrtf(red[0].y / Nn - m * m + 1e-5f));
    }
    __syncthreads();
    float mm = ms.x, rr = ms.y, gg = g[c], bb = b[c];
    int q = (int)blockIdx.x * 256 + tid;
    ushort4 dv = ((const ushort4*)(Dh + (size_t)c * Nn))[q];
    float4 v;
    v.x = fmaxf(gg * (bf2f(dv.x) - mm) * rr + bb, 0.f);
    v.y = fmaxf(gg * (bf2f(dv.y) - mm) * rr + bb, 0.f);
    v.z = fmaxf(gg * (bf2f(dv.z) - mm) * rr + bb, 0.f);
    v.w = fmaxf(gg * (bf2f(dv.w) - mm) * rr + bb, 0.f);
    ((float4*)Y)[(size_t)c * (Nn >> 2) + q] = v;
}

extern "C" void kernel_launch(void* const* d_in, const int* in_sizes, int n_in,
                              void* d_out, int out_size, void* d_ws, size_t ws_size,
                              hipStream_t stream) {
    const float* xyzf = (const float*)d_in[0];
    const float* xyzc = (const float*)d_in[1];
    const float* ff   = (const float*)d_in[2];
    const float* fc   = (const float*)d_in[3];
    const float* W1   = (const float*)d_in[4];
    const float* g1   = (const float*)d_in[5];
    const float* b1   = (const float*)d_in[6];
    const float* W2   = (const float*)d_in[7];
    const float* g2   = (const float*)d_in[8];
    const float* b2   = (const float*)d_in[9];

    int N  = in_sizes[0] / 3;       // 16384
    int M  = in_sizes[1] / 3;       // 4096
    int Cf = in_sizes[2] / N;       // 256
    int Cc = in_sizes[3] / M;       // 512
    int h1 = in_sizes[5];           // 512
    int h2 = in_sizes[8];           // 512
    int Cin = Cc + Cf;              // 768
    float* out = (float*)d_out;

    // workspace carve (~48 MB)
    char* p = (char*)d_ws;
    unsigned short* W1h = (unsigned short*)p; p += (size_t)h1 * Cin * 2;
    unsigned short* W2h = (unsigned short*)p; p += (size_t)h2 * h1 * 2;
    unsigned short* fcT = (unsigned short*)p; p += (size_t)M * Cc * 2;
    int*   idx3 = (int*)p;   p += (size_t)N * 3 * sizeof(int);
    float* w3   = (float*)p; p += (size_t)N * 3 * sizeof(float);
    int NB = N / 128;                                   // 128 GEMM n-blocks
    float* psumG = (float*)p; p += (size_t)NB * h1 * sizeof(float);
    float* psqG  = (float*)p; p += (size_t)NB * h1 * sizeof(float);
    unsigned short* d1h = (unsigned short*)p; p += (size_t)h1 * N * 2;   // y-layout [N][h1] bf16
    unsigned short* xbuf = (unsigned short*)p; p += (size_t)N * Cin * 2;
    // cand records alias d1h: 32B x KCH x N = 16.78 MB = exactly |d1h|.
    float4* cand = (float4*)d1h;
    unsigned short* d2h = xbuf;                         // gemm2 D [h2][N] bf16 (xbuf dead post-gemm1)

    // 1. prologue + kNN scan (independent work fused; prologue blocks first)
    int nW1 = h1 * Cin / 1024, nW2 = h2 * h1 / 1024;
    int Mb = M / 64, nTR = Mb * (Cc / 64);
    int nPro = nW1 + nW2 + nTR;
    scan_pro_kernel<<<nPro + (N / 256) * KCH, 256, 0, stream>>>(
        W1, W2, W1h, W2h, fc, fcT, xyzf, xyzc, cand,
        N, M, Cc, nW1, nW2, nTR, Mb);

    // 2. merge + tr_ff (independent; merge blocks first)
    int nMerge = N / 256, Nb = N / 64, nTF = Nb * (Cf / 64);
    merge_trff_kernel<<<nMerge + nTF, 256, 0, stream>>>(
        cand, xyzf, xyzc, ff, xbuf, idx3, w3, N, M, Cin, Cc, nMerge, Nb);

    // 3. interp (8 channels/thread; 4 points/block)
    interp_kernel<<<N / 4, 256, 0, stream>>>(fcT, idx3, w3, xbuf, Cin, Cc);

    // 4-5. layer 1: gemm1 writes y-layout [N][h1] into d1h; bn1 in place
    gemm_bf16_kernel<1><<<dim3(N / 128, h1 / 128), 256, 0, stream>>>(
        W1h, xbuf, d1h, psumG, psqG, Cin, N, h1);
    bnrelu_ip_kernel<<<dim3(N / 64, h1 / 64), 256, 0, stream>>>(
        d1h, psumG, psqG, g1, b1, N, h1, NB);

    // 6-7. layer 2: gemm2 reads d1h as B, writes [h2][N] into xbuf; bn2 -> out
    gemm_bf16_kernel<0><<<dim3(N / 128, h2 / 128), 256, 0, stream>>>(
        W2h, d1h, d2h, psumG, psqG, h1, N, h2);
    bnrelu2_kernel<<<dim3(N / 1024, h2), 256, 0, stream>>>(
        d2h, out, psumG, psqG, g2, b2, N, h2, NB);
}